// Round 15
// baseline (831.059 us; speedup 1.0000x reference)
//
#include <hip/hip_runtime.h>
#include <math.h>

// Problem dims
#define NB 256
#define DM 126       // D_MODEL
#define DE 128       // D_EMB
#define NH 6
#define DHd 21
#define DFF 2048
#define CIN 75
#define L0 128
#define NTOP 25

#ifndef IDX_MODE
#define IDX_MODE 0
#endif

typedef const float* fp;
typedef unsigned short u16;
typedef short s8v __attribute__((ext_vector_type(8)));
typedef float f4v __attribute__((ext_vector_type(4)));

__device__ __forceinline__ u16 f2bf(float x){
  unsigned u = __float_as_uint(x);
  unsigned r = (u + 0x7FFFu + ((u >> 16) & 1u)) >> 16;
  return (u16)r;
}
__device__ __forceinline__ float bf2f(u16 v){
  unsigned uu = ((unsigned)v) << 16;
  return __uint_as_float(uu);
}

__device__ __forceinline__ void gld_lds16(const u16* g, u16* l){
  __builtin_amdgcn_global_load_lds((const __attribute__((address_space(1))) unsigned int*)(const void*)g,
                                   (__attribute__((address_space(3))) unsigned int*)(void*)l,
                                   16, 0, 0);
}

__device__ __forceinline__ void tf2(unsigned k0, unsigned k1, unsigned x0, unsigned x1,
                                    unsigned &o0, unsigned &o1){
  unsigned ks2 = k0 ^ k1 ^ 0x1BD11BDAu;
  x0 += k0; x1 += k1;
  #define RR(r) { x0 += x1; x1 = (x1 << (r)) | (x1 >> (32 - (r))); x1 ^= x0; }
  RR(13) RR(15) RR(26) RR(6)
  x0 += k1;  x1 += ks2 + 1u;
  RR(17) RR(29) RR(16) RR(24)
  x0 += ks2; x1 += k0 + 2u;
  RR(13) RR(15) RR(26) RR(6)
  x0 += k0;  x1 += k1 + 3u;
  RR(17) RR(29) RR(16) RR(24)
  x0 += k1;  x1 += ks2 + 4u;
  RR(13) RR(15) RR(26) RR(6)
  x0 += ks2; x1 += k0 + 5u;
  #undef RR
  o0 = x0; o1 = x1;
}

// ---------------- fallback: zero output (ws too small diagnostic) ----------------
__global__ __launch_bounds__(256) void k_zero(float* out, int n){
  int i = blockIdx.x*256 + threadIdx.x;
  if (i < n) out[i] = 0.f;
}

// ---------------- idx precompute ----------------
__global__ __launch_bounds__(256) void k_idx(int* idx0, int* idx1){
  int tid = threadIdx.x;
  unsigned a0,a1,c0,c1;
  tf2(0u,42u, 0u,0u, a0,a1);
  tf2(0u,42u, 0u,1u, c0,c1);
  for (int f = tid; f < 3200; f += 256){
    unsigned y0,y1;
#if IDX_MODE==0
    tf2(a0,a1, 0u, (unsigned)(3200+f), y0,y1); idx0[f] = (int)(y1 & 127u);
#elif IDX_MODE==1
    tf2(a0,a1, 0u, (unsigned)(3200+f), y0,y1); idx0[f] = (int)(y0 & 127u);
#elif IDX_MODE==2
    tf2(a0,a1, (unsigned)f, (unsigned)(3200+f), y0,y1); idx0[f] = (int)(y1 & 127u);
#else
    tf2(a0,a1, (unsigned)f, (unsigned)(3200+f), y0,y1); idx0[f] = (int)(y0 & 127u);
#endif
  }
  for (int f = tid; f < 1600; f += 256){
    unsigned y0,y1;
#if IDX_MODE==0
    tf2(c0,c1, 0u, (unsigned)(1600+f), y0,y1); idx1[f] = (int)(y1 & 63u);
#elif IDX_MODE==1
    tf2(c0,c1, 0u, (unsigned)(1600+f), y0,y1); idx1[f] = (int)(y0 & 63u);
#elif IDX_MODE==2
    tf2(c0,c1, (unsigned)f, (unsigned)(1600+f), y0,y1); idx1[f] = (int)(y1 & 63u);
#else
    tf2(c0,c1, (unsigned)f, (unsigned)(1600+f), y0,y1); idx1[f] = (int)(y0 & 63u);
#endif
  }
}

// ---------------- unified weight prep (both layers) ----------------
__global__ __launch_bounds__(256) void k_wprep(fp token_w, fp clw,
                                               fp qw, fp qb, fp kw, fp kb, fp vw, fp vb, fp ow,
                                               fp f1w, fp f2w,
                                               u16* wemb, u16* wdist, u16* wqkv, u16* wo,
                                               u16* w1t, u16* w2t, float* qbias){
  int i = blockIdx.x*256 + threadIdx.x;
  if (i < 32768){
    int n = i >> 8, k = i & 255;
    float v = 0.f;
    if (k < 225){ int q = k/75, c = k - q*75; v = token_w[(size_t)n*225 + c*3 + q]; }
    wemb[i] = f2bf(v);
    return;
  }
  i -= 32768;
  if (i < 49152){
    int n = i / 384, k = i - n*384;
    float v = 0.f;
    if (n < DM && k < 378){ int q = k/126, ci = k - q*126; v = clw[((size_t)n*DM + ci)*3 + q]; }
    wdist[i] = f2bf(v);
    return;
  }
  i -= 49152;
  if (i < 2*49152){
    int layer = i / 49152, jj = i - layer*49152;
    int n = jj >> 7, k = jj & 127;
    int sec = n >> 7, nn = n & 127;
    const float* w = (sec == 0) ? qw : ((sec == 1) ? kw : vw);
    float v = (nn < DM && k < DM) ? w[((size_t)layer*DM + k)*DM + nn] : 0.f;
    wqkv[(size_t)layer*49152 + jj] = f2bf(v);
    return;
  }
  i -= 2*49152;
  if (i < 2*16384){
    int layer = i / 16384, jj = i - layer*16384;
    int n = jj >> 7, k = jj & 127;
    float v = (n < DM && k < DM) ? ow[(size_t)layer*DM*DM + k*DM + n] : 0.f;
    wo[(size_t)layer*16384 + jj] = f2bf(v);
    return;
  }
  i -= 2*16384;
  if (i < 2*262144){
    int layer = i / 262144, jj = i - layer*262144;
    int n = jj >> 7, k = jj & 127;
    float v = (k < DM) ? f1w[((size_t)layer*DM + k)*DFF + n] : 0.f;
    w1t[(size_t)layer*262144 + jj] = f2bf(v);
    return;
  }
  i -= 2*262144;
  if (i < 2*262144){
    int layer = i / 262144, jj = i - layer*262144;
    int n = jj >> 11, f = jj & 2047;
    float v = (n < DM) ? f2w[((size_t)layer*DFF + f)*DM + n] : 0.f;
    w2t[(size_t)layer*262144 + jj] = f2bf(v);
    return;
  }
  i -= 2*262144;
  if (i < 768){
    int layer = i / 384, n = i - layer*384;
    int sec = n >> 7, nn = n & 127;
    const float* bp = (sec == 0) ? qb : ((sec == 1) ? kb : vb);
    qbias[(size_t)layer*384 + n] = (nn < DM) ? bp[layer*DM + nn] : 0.f;
  }
}

// ---------------- MFMA token-embed: conv(K=225) + pos + time, out emb[b][l][e] ----------------
__global__ __launch_bounds__(256) void k_emb_mfma(fp x_enc, fp x_mark, const u16* wemb,
                                                  fp time_w, fp time_b, float* emb){
  __shared__ __align__(16) u16 sA[128*264];
  const int tid = threadIdx.x;
  const int wave = tid >> 6, lane = tid & 63, quad = lane >> 4, l15 = lane & 15;
  const int b = blockIdx.x;
  for (int p = tid; p < 128*256; p += 256){
    int kk = p & 255, row = p >> 8;
    float v = 0.f;
    if (kk < 225){
      int q = kk / 75, c = kk - q*75;
      int sr = (row - 1 + q + 128) & 127;
      v = x_enc[((size_t)b*L0 + sr)*CIN + c];
    }
    sA[row*264 + kk] = f2bf(v);
  }
  __syncthreads();
  const f4v z4 = {0.f,0.f,0.f,0.f};
  f4v acc[2][8];
  #pragma unroll
  for (int m = 0; m < 2; m++)
    #pragma unroll
    for (int t = 0; t < 8; t++) acc[m][t] = z4;
  const int mBase = wave * 32;
  for (int ks = 0; ks < 8; ks++){
    s8v a0 = *reinterpret_cast<const s8v*>(sA + (mBase + l15)*264 + ks*32 + quad*8);
    s8v a1 = *reinterpret_cast<const s8v*>(sA + (mBase + 16 + l15)*264 + ks*32 + quad*8);
    const u16* wb = wemb + (size_t)l15*256 + ks*32 + quad*8;
    #pragma unroll
    for (int t = 0; t < 8; t++){
      s8v bfr = *reinterpret_cast<const s8v*>(wb + (size_t)t*16*256);
      acc[0][t] = __builtin_amdgcn_mfma_f32_16x16x32_bf16(a0, bfr, acc[0][t], 0, 0, 0);
      acc[1][t] = __builtin_amdgcn_mfma_f32_16x16x32_bf16(a1, bfr, acc[1][t], 0, 0, 0);
    }
  }
  #pragma unroll
  for (int t = 0; t < 8; t++){
    int col = t*16 + l15;
    int i2 = col >> 1;
    float div = __expf((float)(2*i2) * (-9.210340371976184f / 128.f));
    float tw0 = time_w[col], tw1 = time_w[128 + col], tw2 = time_w[256 + col];
    float tb = time_b[col];
    #pragma unroll
    for (int m = 0; m < 2; m++){
      #pragma unroll
      for (int r = 0; r < 4; r++){
        int row = mBase + m*16 + quad*4 + r;
        float ang = (float)row * div;
        float pe = (col & 1) ? cosf(ang) : sinf(ang);
        const float* mk = x_mark + ((size_t)b*L0 + row)*3;
        float tm = mk[0]*tw0 + mk[1]*tw1 + mk[2]*tw2 + tb;
        emb[((size_t)b*L0 + row)*DE + col] = acc[m][t][r] + pe + tm;
      }
    }
  }
}

// ---------------- per-batch attention scalars (emb layout [b][l][e]) ----------------
__global__ __launch_bounds__(128) void k_scalars(const float* emb, fp fcw, fp bng, fp bnb,
                                                 fp chw, fp chb, fp filw, fp filb,
                                                 fp spw, fp spb, fp kerw, fp kerb,
                                                 float* ch, float* fil, float* sp, float* ker){
  __shared__ float gap[DE];
  __shared__ float a[16];
  int b = blockIdx.x, t = threadIdx.x;
  float s = 0.f;
  for (int l = 0; l < L0; l++) s += emb[((size_t)b*L0 + l)*DE + t];
  gap[t] = s / (float)L0;
  __syncthreads();
  if (t < 16){
    float acc = 0.f;
    for (int e = 0; e < DE; e++) acc += gap[e]*fcw[e*16 + t];
    acc = acc * (bng[t] / sqrtf(1.f + 1e-5f)) + bnb[t];
    a[t] = fmaxf(acc, 0.f);
  }
  __syncthreads();
  float accc = 0.f, accf = 0.f;
  for (int c = 0; c < 16; c++){ accc += a[c]*chw[c*DE + t]; accf += a[c]*filw[c*DE + t]; }
  ch[b*DE + t]  = 1.f/(1.f + expf(-(accc + chb[t])));
  fil[b*DE + t] = 1.f/(1.f + expf(-(accf + filb[t])));
  if (t < 3){
    float acc = 0.f;
    for (int c = 0; c < 16; c++) acc += a[c]*spw[c*3 + t];
    sp[b*4 + t] = 1.f/(1.f + expf(-(acc + spb[t])));
  }
  if (t == 0){
    float v[4]; float mx = -1e30f;
    for (int n = 0; n < 4; n++){
      float acc = 0.f;
      for (int c = 0; c < 16; c++) acc += a[c]*kerw[c*4 + n];
      v[n] = acc + kerb[n]; mx = fmaxf(mx, v[n]);
    }
    float ss = 0.f;
    for (int n = 0; n < 4; n++){ v[n] = expf(v[n]-mx); ss += v[n]; }
    for (int n = 0; n < 4; n++) ker[b*4 + n] = v[n]/ss;
  }
}

// ---------------- MFMA ODConv ----------------
__global__ __launch_bounds__(256) void k_odconv_mfma(const float* emb, fp odw,
                                                     const float* ch, const float* fil,
                                                     const float* sp, const float* ker, float* xout){
  __shared__ __align__(16) u16 sXT[130*136];
  __shared__ __align__(16) u16 sW[3*128*136];
  const int tid = threadIdx.x;
  const int wave = tid >> 6, lane = tid & 63, quad = lane >> 4, l15 = lane & 15;
  const int b = blockIdx.x;
  for (int p = tid; p < 130*128; p += 256){
    int l = p >> 7, i = p & 127;
    float v = 0.f;
    if (l < 128) v = emb[((size_t)b*L0 + l)*DE + i] * ch[b*DE + i];
    sXT[l*136 + i] = f2bf(v);
  }
  float kr0 = ker[b*4+0], kr1 = ker[b*4+1], kr2 = ker[b*4+2], kr3 = ker[b*4+3];
  float spv[3]; spv[0] = sp[b*4+0]; spv[1] = sp[b*4+1]; spv[2] = sp[b*4+2];
  const float4* od4 = (const float4*)odw;
  for (int p4 = tid; p4 < 128*384/4; p4 += 256){
    float4 w0 = od4[p4];
    float4 w1 = od4[12288 + p4];
    float4 w2 = od4[24576 + p4];
    float4 w3 = od4[36864 + p4];
    float vv[4] = { kr0*w0.x + kr1*w1.x + kr2*w2.x + kr3*w3.x,
                    kr0*w0.y + kr1*w1.y + kr2*w2.y + kr3*w3.y,
                    kr0*w0.z + kr1*w1.z + kr2*w2.z + kr3*w3.z,
                    kr0*w0.w + kr1*w1.w + kr2*w2.w + kr3*w3.w };
    int e0 = p4*4;
    #pragma unroll
    for (int j = 0; j < 4; j++){
      int e = e0 + j;
      int o = e / 384, rem = e - o*384;
      int i = rem / 3, q = rem - i*3;
      sW[(q*128 + o)*136 + i] = f2bf(vv[j] * spv[q]);
    }
  }
  __syncthreads();
  const f4v z4 = {0.f,0.f,0.f,0.f};
  f4v acc[2][8];
  #pragma unroll
  for (int m = 0; m < 2; m++)
    #pragma unroll
    for (int t = 0; t < 8; t++) acc[m][t] = z4;
  const int mBase = wave * 32;
  for (int q = 0; q < 3; q++){
    const u16* wq = sW + q*128*136;
    #pragma unroll
    for (int ks = 0; ks < 4; ks++){
      s8v a0 = *reinterpret_cast<const s8v*>(wq + (mBase + l15)*136 + ks*32 + quad*8);
      s8v a1 = *reinterpret_cast<const s8v*>(wq + (mBase + 16 + l15)*136 + ks*32 + quad*8);
      #pragma unroll
      for (int t = 0; t < 8; t++){
        s8v bfr = *reinterpret_cast<const s8v*>(sXT + (t*16 + l15 + q)*136 + ks*32 + quad*8);
        acc[0][t] = __builtin_amdgcn_mfma_f32_16x16x32_bf16(a0, bfr, acc[0][t], 0, 0, 0);
        acc[1][t] = __builtin_amdgcn_mfma_f32_16x16x32_bf16(a1, bfr, acc[1][t], 0, 0, 0);
      }
    }
  }
  #pragma unroll
  for (int t = 0; t < 8; t++){
    int tt = t*16 + l15;
    if (tt < DM){
      #pragma unroll
      for (int m = 0; m < 2; m++){
        #pragma unroll
        for (int r = 0; r < 4; r++){
          int o = mBase + m*16 + quad*4 + r;
          xout[((size_t)b*DE + o)*DM + tt] = fil[b*DE + o] * acc[m][t][r];
        }
      }
    }
  }
}

// ---------------- fused QKV GEMM: qkv[M][384] ----------------
__global__ __launch_bounds__(256) void k_qkv_mfma(const float* xin, const u16* wqkv,
                                                  const float* qkvb, float* qkv){
  __shared__ __align__(16) u16 sX[64*136];
  const int tid = threadIdx.x;
  const int wave = tid >> 6, lane = tid & 63, quad = lane >> 4, l15 = lane & 15;
  const size_t rows0 = (size_t)blockIdx.x * 64;
  for (int p = tid; p < 64*128; p += 256){
    int r = p >> 7, c = p & 127;
    float v = (c < DM) ? xin[(rows0 + r)*DM + c] : 0.f;
    sX[r*136 + c] = f2bf(v);
  }
  __syncthreads();
  const f4v z4 = {0.f,0.f,0.f,0.f};
  f4v acc[24];
  #pragma unroll
  for (int t = 0; t < 24; t++) acc[t] = z4;
  const int m0 = wave * 16;
  #pragma unroll
  for (int ks = 0; ks < 4; ks++){
    s8v a = *reinterpret_cast<const s8v*>(sX + (m0 + l15)*136 + ks*32 + quad*8);
    const u16* wb = wqkv + (size_t)l15*128 + ks*32 + quad*8;
    #pragma unroll
    for (int t = 0; t < 24; t++){
      s8v b = *reinterpret_cast<const s8v*>(wb + (size_t)t*16*128);
      acc[t] = __builtin_amdgcn_mfma_f32_16x16x32_bf16(a, b, acc[t], 0, 0, 0);
    }
  }
  #pragma unroll
  for (int t = 0; t < 24; t++){
    int col = t*16 + l15;
    float bv = qkvb[col];
    #pragma unroll
    for (int r = 0; r < 4; r++){
      int row = m0 + quad*4 + r;
      qkv[(rows0 + row)*384 + col] = acc[t][r] + bv;
    }
  }
}

// ---------------- attention phase 1: exact M + top-k selection (one wave per bh) ----------------
__global__ __launch_bounds__(256) void k_attn_sel(const float* qkv, const int* idx, int L,
                                                  int* posmap, int* stopb){
  __shared__ float smem[4*2816];
  const int tid = threadIdx.x;
  const int wave = tid >> 6, lane = tid & 63;
  const int bh = blockIdx.x*4 + wave;
  const int b = bh / NH, h = bh - b*NH;
  float* sK = smem + wave*2816;
  float* sM = sK + 2688;
  const float* qbase = qkv + (size_t)(b*L)*384 + h*DHd;
  for (int p = lane; p < L*DHd; p += 64){
    int l = p / DHd, d = p - l*DHd;
    sK[p] = qbase[(size_t)l*384 + 128 + d];
  }
  posmap[bh*L0 + lane] = -1;
  if (L == 128) posmap[bh*L0 + 64 + lane] = -1;
  __syncthreads();
  int nr = (L == 128) ? 2 : 1;
  for (int rr = 0; rr < nr; rr++){
    int l = lane + rr*64;
    const float* qg = qbase + (size_t)l*384;
    float qr[DHd];
    #pragma unroll
    for (int d = 0; d < DHd; d++) qr[d] = qg[d];
    float mx = -1e30f, sm = 0.f;
    #pragma unroll
    for (int u = 0; u < NTOP; u++){
      int kk = idx[l*NTOP + u];
      const float* kp = sK + kk*DHd;
      float acc = 0.f;
      #pragma unroll
      for (int d = 0; d < DHd; d++) acc += qr[d]*kp[d];
      mx = fmaxf(mx, acc); sm += acc;
    }
    sM[l] = mx - sm/(float)L;
  }
  for (int it = 0; it < NTOP; it++){
    float bv = sM[lane]; int bi = lane;
    if (L == 128){
      float v1 = sM[lane + 64];
      if (v1 > bv){ bv = v1; bi = lane + 64; }
    }
    #pragma unroll
    for (int off = 32; off > 0; off >>= 1){
      float ov = __shfl_xor(bv, off);
      int   oi = __shfl_xor(bi, off);
      if (ov > bv || (ov == bv && oi < bi)){ bv = ov; bi = oi; }
    }
    if (lane == 0){
      sM[bi] = -1e30f;
      posmap[bh*L0 + bi] = it;
      stopb[bh*NTOP + it] = bi;
    }
  }
}

// ---------------- attention phase 2: softmax(QselK^T)V via MFMA, LDS = P only ----------------
#define PV_SLICE 4352
__global__ __launch_bounds__(256) void k_attn_pv(const float* qkv, const int* stopb, int L,
                                                 float* vmean, float* upd){
  __shared__ __align__(16) u16 smem[4*PV_SLICE];
  const int tid = threadIdx.x;
  const int wave = tid >> 6, lane = tid & 63, quad = lane >> 4, l15 = lane & 15;
  const int bh = blockIdx.x*4 + wave;
  const int b = bh / NH, h = bh - b*NH;
  u16* sPb = smem + wave*PV_SLICE;
  const float* qbase = qkv + (size_t)(b*L)*384 + h*DHd;
  const f4v z4 = {0.f,0.f,0.f,0.f};
  const int ntn = L >> 4;
  const int d0 = quad*8;

  f4v sc[2][8];
  #pragma unroll
  for (int mt = 0; mt < 2; mt++){
    int uu = mt*16 + l15; if (uu >= NTOP) uu = 0;
    int r = stopb[bh*NTOP + uu];
    const float* qp = qbase + (size_t)r*384 + d0;
    s8v a;
    #pragma unroll
    for (int j = 0; j < 8; j++) a[j] = (short)f2bf(qp[j]);
    for (int nt = 0; nt < ntn; nt++){
      const float* kp = qbase + 128 + (size_t)(nt*16 + l15)*384 + d0;
      s8v bb;
      #pragma unroll
      for (int j = 0; j < 8; j++) bb[j] = (d0 + j < DHd) ? (short)f2bf(kp[j]) : (short)0;
      sc[mt][nt] = __builtin_amdgcn_mfma_f32_16x16x32_bf16(a, bb, z4, 0, 0, 0);
    }
  }
  const float inv21 = 0.21821789023599236f;   // 1/sqrt(21)
  #pragma unroll
  for (int mt = 0; mt < 2; mt++){
    #pragma unroll
    for (int r4 = 0; r4 < 4; r4++){
      float mx = -1e30f;
      for (int nt = 0; nt < ntn; nt++) mx = fmaxf(mx, sc[mt][nt][r4]*inv21);
      #pragma unroll
      for (int off = 1; off < 16; off <<= 1) mx = fmaxf(mx, __shfl_xor(mx, off));
      float e[8]; float ss = 0.f;
      for (int nt = 0; nt < ntn; nt++){ e[nt] = expf(sc[mt][nt][r4]*inv21 - mx); ss += e[nt]; }
      #pragma unroll
      for (int off = 1; off < 16; off <<= 1) ss += __shfl_xor(ss, off);
      float dn = 1.f / ss;
      int u = mt*16 + quad*4 + r4;
      for (int nt = 0; nt < ntn; nt++)
        sPb[u*136 + nt*16 + l15] = f2bf(e[nt]*dn);
    }
  }
  {
    u16 invL = f2bf(1.f/(float)L);
    for (int c = lane; c < L; c += 64) sPb[25*136 + c] = invL;
  }
  f4v pv[2][2];
  pv[0][0]=z4; pv[0][1]=z4; pv[1][0]=z4; pv[1][1]=z4;
  int kSteps = L >> 5;
  for (int ks = 0; ks < kSteps; ks++){
    #pragma unroll
    for (int nt = 0; nt < 2; nt++){
      const float* vp = qbase + 256 + (size_t)(ks*32 + d0)*384 + nt*16 + l15;
      s8v bb;
      #pragma unroll
      for (int j = 0; j < 8; j++) bb[j] = (short)f2bf(vp[(size_t)j*384]);
      #pragma unroll
      for (int mt = 0; mt < 2; mt++){
        s8v a = *reinterpret_cast<const s8v*>(sPb + (mt*16 + l15)*136 + ks*32 + d0);
        pv[mt][nt] = __builtin_amdgcn_mfma_f32_16x16x32_bf16(a, bb, pv[mt][nt], 0, 0, 0);
      }
    }
  }
  #pragma unroll
  for (int mt = 0; mt < 2; mt++){
    #pragma unroll
    for (int nt = 0; nt < 2; nt++){
      #pragma unroll
      for (int r4 = 0; r4 < 4; r4++){
        int u = mt*16 + quad*4 + r4;
        int d = nt*16 + l15;
        if (d < DHd){
          if (u < NTOP)       upd[((size_t)bh*NTOP + u)*DHd + d] = pv[mt][nt][r4];
          else if (u == NTOP) vmean[bh*DHd + d] = pv[mt][nt][r4];
        }
      }
    }
  }
}

// ---------------- MFMA O-proj + residual + LN1 (64 rows / block) ----------------
__global__ __launch_bounds__(256) void k_oproj_mfma(const float* xin, const float* vmean,
                                                    const int* posmap, const float* upd,
                                                    const u16* wo, fp ob, fp g, fp bb,
                                                    int layer, int lshift, int lmask, float* xmid){
  __shared__ __align__(16) float sOf[64*129];
  __shared__ float prs[128];
  __shared__ float smean[64], srstd[64];
  u16* sX = reinterpret_cast<u16*>(sOf);
  const int tid = threadIdx.x;
  const int wave = tid >> 6, lane = tid & 63, quad = lane >> 4, l15 = lane & 15;
  const int m0 = wave * 16;
  const size_t rows0 = (size_t)blockIdx.x * 64;
  for (int p = tid; p < 64*128; p += 256){
    int r = p >> 7, c = p & 127;
    int gr = (int)rows0 + r, b = gr >> lshift, l = gr & lmask;
    float v = 0.f;
    if (c < DM){
      int h = c / DHd, d = c - h*DHd;
      int bh = b*NH + h;
      int pos = posmap[bh*L0 + l];
      v = (pos >= 0) ? upd[((size_t)bh*NTOP + pos)*DHd + d] : vmean[bh*DHd + d];
    }
    sX[r*136 + c] = f2bf(v);
  }
  __syncthreads();
  const f4v z4 = {0.f,0.f,0.f,0.f};
  f4v acc[8];
  #pragma unroll
  for (int t = 0; t < 8; t++) acc[t] = z4;
  #pragma unroll
  for (int ks = 0; ks < 4; ks++){
    s8v a = *reinterpret_cast<const s8v*>(sX + (m0 + l15)*136 + ks*32 + quad*8);
    const u16* wb = wo + (size_t)l15*128 + ks*32 + quad*8;
    #pragma unroll
    for (int t = 0; t < 8; t++){
      s8v b = *reinterpret_cast<const s8v*>(wb + (size_t)t*16*128);
      acc[t] = __builtin_amdgcn_mfma_f32_16x16x32_bf16(a, b, acc[t], 0, 0, 0);
    }
  }
  __syncthreads();
  #pragma unroll
  for (int t = 0; t < 8; t++){
    int col = t*16 + l15;
    #pragma unroll
    for (int r = 0; r < 4; r++){
      sOf[(m0 + quad*4 + r)*129 + col] = acc[t][r];
    }
  }
  __syncthreads();
  const float* obl = ob + (size_t)layer*DM;
  for (int p = tid; p < 64*DM; p += 256){
    int r = p / DM, c = p - r*DM;
    sOf[r*129 + c] += xin[(rows0 + r)*DM + c] + obl[c];
  }
  __syncthreads();
  if (tid < 128){
    int row = tid >> 1, half = tid & 1;
    float s = 0.f;
    for (int c = half*63; c < half*63 + 63; c++) s += sOf[row*129 + c];
    prs[tid] = s;
  }
  __syncthreads();
  if (tid < 128 && (tid & 1) == 0) smean[tid>>1] = (prs[tid] + prs[tid+1]) / (float)DM;
  __syncthreads();
  if (tid < 128){
    int row = tid >> 1, half = tid & 1;
    float mn = smean[row];
    float s = 0.f;
    for (int c = half*63; c < half*63 + 63; c++){ float d = sOf[row*129 + c] - mn; s += d*d; }
    prs[tid] = s;
  }
  __syncthreads();
  if (tid < 128 && (tid & 1) == 0) srstd[tid>>1] = rsqrtf((prs[tid] + prs[tid+1])/(float)DM + 1e-5f);
  __syncthreads();
  const float* gl = g  + (size_t)layer*DM;
  const float* bl = bb + (size_t)layer*DM;
  for (int p = tid; p < 64*DM; p += 256){
    int r = p / DM, c = p - r*DM;
    xmid[(rows0 + r)*DM + c] = (sOf[r*129 + c] - smean[r])*srstd[r]*gl[c] + bl[c];
  }
}

// fast GELU: tanh form, x*t/(t+1) with t=exp(1.5957691x + 0.0713548x^3)
__device__ __forceinline__ float gelu_fast(float x){
  float x2 = x*x;
  float u = x * __builtin_fmaf(0.07135481f, x2, 1.5957691f);
  u = fminf(u, 85.f);
  float t = __expf(u);
  return x * t * __builtin_amdgcn_rcpf(t + 1.f);
}

// ---------------- MFMA FFN + residual + LN2 — 512 thr / 128 rows, reg A-frags, dual ping-pong ----
// smem (u16): sY 8*1152=9216 | wA0 8192 | wA1 8192 | wB0 8192 | wB1 8192 => 41984 u16 = 83,968 B
// epilogue reuses smem as fp32 [128][129] = 66,048 B
#define FFN_SMEM_U16 (9216 + 4*8192)

__device__ __forceinline__ void stage_w1_512(const u16* w1t, int j, u16* buf, int tid){
  #pragma unroll
  for (int r = 0; r < 2; r++){
    int p = r*512 + tid;
    int n = p >> 4, c = p & 15;
    int cg = c ^ (n & 7);
    const u16* g = w1t + (((size_t)(j*64 + n)) << 7) + cg*8;
    u16* l = buf + (size_t)((p >> 6) << 6)*8;   // group base: 64 lanes x 8 u16
    gld_lds16(g, l);
  }
}
__device__ __forceinline__ void stage_w2_512(const u16* w2t, int j, u16* buf, int tid){
  #pragma unroll
  for (int r = 0; r < 2; r++){
    int p = r*512 + tid;
    int n = p >> 3, c = p & 7;
    int cg = c ^ (n & 7);
    const u16* g = w2t + (size_t)n*2048 + j*64 + cg*8;
    u16* l = buf + (size_t)((p >> 6) << 6)*8;
    gld_lds16(g, l);
  }
}

__global__ __launch_bounds__(512) void k_ffn_mfma(const float* xmid, const u16* w1t, const u16* w2t,
                                                  fp b1, fp b2w, fp g, fp bb, int layer, float* xout){
  __shared__ __align__(16) u16 smem[FFN_SMEM_U16];
  __shared__ float prs[256];
  __shared__ float smean[128], srstd[128];
  u16* wA0 = smem + 9216;
  u16* wA1 = wA0 + 8192;
  u16* wB0 = wA1 + 8192;
  u16* wB1 = wB0 + 8192;
  const int tid  = threadIdx.x;
  const int wave = tid >> 6, lane = tid & 63, quad = lane >> 4, l15 = lane & 15;
  const int m0 = wave * 16;
  u16* sYw = smem + wave*1152;   // 16 rows x 72 stride, wave-private
  const size_t rows0 = (size_t)blockIdx.x * 128;

  // X A-frags in registers: rows m0+l15, all K=128 (4 frags)
  s8v aX[4];
  {
    const float* xr = xmid + (rows0 + m0 + l15)*(size_t)DM;
    #pragma unroll
    for (int ks = 0; ks < 4; ks++){
      #pragma unroll
      for (int j = 0; j < 8; j++){
        int c = ks*32 + quad*8 + j;
        float v = (c < DM) ? xr[c] : 0.f;
        aX[ks][j] = (short)f2bf(v);
      }
    }
  }
  stage_w1_512(w1t, 0, wA0, tid);
  stage_w2_512(w2t, 0, wB0, tid);
  __syncthreads();

  const float* b1l = b1 + (size_t)layer*DFF;
  const f4v z4 = {0.f, 0.f, 0.f, 0.f};
  f4v acc2[8];
  #pragma unroll
  for (int t = 0; t < 8; t++) acc2[t] = z4;

  for (int j = 0; j < 32; j++){
    u16* wAcur = (j & 1) ? wA1 : wA0;
    u16* wAnxt = (j & 1) ? wA0 : wA1;
    u16* wBcur = (j & 1) ? wB1 : wB0;
    u16* wBnxt = (j & 1) ? wB0 : wB1;
    if (j < 31){
      stage_w1_512(w1t, j+1, wAnxt, tid);
      stage_w2_512(w2t, j+1, wBnxt, tid);
    }
    // GEMM1: 16 rows x 64 cols, K=128 (A from registers)
    f4v acc1[4];
    #pragma unroll
    for (int t = 0; t < 4; t++) acc1[t] = z4;
    #pragma unroll
    for (int ks = 0; ks < 4; ks++){
      #pragma unroll
      for (int t = 0; t < 4; t++){
        int nloc = t*16 + l15;
        int cg = (ks*4 + quad) ^ (nloc & 7);
        s8v b = *reinterpret_cast<const s8v*>(wAcur + nloc*128 + cg*8);
        acc1[t] = __builtin_amdgcn_mfma_f32_16x16x32_bf16(aX[ks], b, acc1[t], 0, 0, 0);
      }
    }
    // bias + GELU -> sY (wave-private; LDS ops wave-ordered, no barrier before GEMM2)
    #pragma unroll
    for (int t = 0; t < 4; t++){
      float bv = b1l[j*64 + t*16 + l15];
      #pragma unroll
      for (int r = 0; r < 4; r++){
        float v = gelu_fast(acc1[t][r] + bv);
        sYw[(quad*4 + r)*72 + t*16 + l15] = f2bf(v);
      }
    }
    // GEMM2: K=64 from sY, N=128, accumulate
    #pragma unroll
    for (int ks = 0; ks < 2; ks++){
      s8v a2 = *reinterpret_cast<const s8v*>(sYw + l15*72 + ks*32 + quad*8);
      #pragma unroll
      for (int t = 0; t < 8; t++){
        int nloc = t*16 + l15;
        int cg = (ks*4 + quad) ^ (nloc & 7);
        s8v b = *reinterpret_cast<const s8v*>(wBcur + nloc*64 + cg*8);
        acc2[t] = __builtin_amdgcn_mfma_f32_16x16x32_bf16(a2, b, acc2[t], 0, 0, 0);
      }
    }
    __syncthreads();   // generation swap: drains prefetch, fences cur-buffer reads
  }

  // epilogue: reuse smem as fp32 [128][129]
  float* sO = reinterpret_cast<float*>(smem);
  #pragma unroll
  for (int t = 0; t < 8; t++){
    int col = t*16 + l15;
    #pragma unroll
    for (int r = 0; r < 4; r++){
      sO[(m0 + quad*4 + r)*129 + col] = acc2[t][r];
    }
  }
  __syncthreads();
  const float* b2l = b2w + (size_t)layer*DM;
  for (int p = tid; p < 128*DM; p += 512){
    int r = p / DM, c = p - r*DM;
    sO[r*129 + c] += b2l[c] + xmid[(rows0 + r)*DM + c];
  }
  __syncthreads();
  if (tid < 256){
    int row = tid >> 1, half = tid & 1;
    float s = 0.f;
    for (int c = half*63; c < half*63 + 63; c++) s += sO[row*129 + c];
    prs[tid] = s;
  }
  __syncthreads();
  if (tid < 256 && (tid & 1) == 0) smean[tid>>1] = (prs[tid] + prs[tid+1]) / (float)DM;
  __syncthreads();
  if (tid < 256){
    int row = tid >> 1, half = tid & 1;
    float mn = smean[row];
    float s = 0.f;
    for (int c = half*63; c < half*63 + 63; c++){ float d = sO[row*129 + c] - mn; s += d*d; }
    prs[tid] = s;
  }
  __syncthreads();
  if (tid < 256 && (tid & 1) == 0) srstd[tid>>1] = rsqrtf((prs[tid] + prs[tid+1])/(float)DM + 1e-5f);
  __syncthreads();
  const float* gl = g  + (size_t)layer*DM;
  const float* bl = bb + (size_t)layer*DM;
  for (int p = tid; p < 128*DM; p += 512){
    int r = p / DM, c = p - r*DM;
    xout[(rows0 + r)*DM + c] = (sO[r*129 + c] - smean[r])*srstd[r]*gl[c] + bl[c];
  }
}

// ---------------- MFMA distil: conv(K=378) + BN + ELU + maxpool ----------------
__global__ __launch_bounds__(256) void k_distill_mfma(const float* xin, const u16* wdist,
                                                      fp clb, fp bng, fp bnb, float* xout){
  __shared__ __align__(16) u16 sA[128*392];
  const int tid = threadIdx.x;
  const int wave = tid >> 6, lane = tid & 63, quad = lane >> 4, l15 = lane & 15;
  const int b = blockIdx.x;
  for (int row = wave; row < 128; row += 4){
    #pragma unroll
    for (int e = 0; e < 6; e++){
      int kk = lane + e*64;
      float v = 0.f;
      if (kk < 378){
        int q = kk / 126, ci = kk - q*126;
        int sr = (row - 1 + q + 128) & 127;
        v = xin[((size_t)b*128 + sr)*DM + ci];
      }
      sA[row*392 + kk] = f2bf(v);
    }
  }
  __syncthreads();
  const f4v z4 = {0.f,0.f,0.f,0.f};
  f4v acc[2][8];
  #pragma unroll
  for (int m = 0; m < 2; m++)
    #pragma unroll
    for (int t = 0; t < 8; t++) acc[m][t] = z4;
  const int mBase = wave * 32;
  for (int ks = 0; ks < 12; ks++){
    s8v a0 = *reinterpret_cast<const s8v*>(sA + (mBase + l15)*392 + ks*32 + quad*8);
    s8v a1 = *reinterpret_cast<const s8v*>(sA + (mBase + 16 + l15)*392 + ks*32 + quad*8);
    const u16* wb = wdist + (size_t)l15*384 + ks*32 + quad*8;
    #pragma unroll
    for (int t = 0; t < 8; t++){
      s8v bfr = *reinterpret_cast<const s8v*>(wb + (size_t)t*16*384);
      acc[0][t] = __builtin_amdgcn_mfma_f32_16x16x32_bf16(a0, bfr, acc[0][t], 0, 0, 0);
      acc[1][t] = __builtin_amdgcn_mfma_f32_16x16x32_bf16(a1, bfr, acc[1][t], 0, 0, 0);
    }
  }
  __syncthreads();
  float* zsh = reinterpret_cast<float*>(sA);
  const float bnscale = 1.f / sqrtf(1.f + 1e-5f);
  #pragma unroll
  for (int t = 0; t < 8; t++){
    int co = t*16 + l15;
    if (co < DM){
      float cb = clb[co];
      float gg = bng[co] * bnscale, bv = bnb[co];
      #pragma unroll
      for (int m = 0; m < 2; m++){
        #pragma unroll
        for (int r = 0; r < 4; r++){
          int row = mBase + m*16 + quad*4 + r;
          float z = (acc[m][t][r] + cb)*gg + bv;
          z = (z > 0.f) ? z : expm1f(z);
          zsh[row*130 + co] = z;
        }
      }
    }
  }
  __syncthreads();
  for (int p = tid; p < 64*DM; p += 256){
    int j = p / DM, co = p - j*DM;
    float best = zsh[(2*j)*130 + co];
    if (j > 0) best = fmaxf(best, zsh[(2*j - 1)*130 + co]);
    best = fmaxf(best, zsh[(2*j + 1)*130 + co]);
    xout[((size_t)b*64 + j)*DM + co] = best;
  }
}

// ---------------- final LN + fc ----------------
__global__ __launch_bounds__(128) void k_final(const float* xin, fp g, fp bb,
                                               fp fcw, fp fcb, float* out){
  __shared__ float xs[64][DM];
  __shared__ float mean_s[64], rstd_s[64];
  int b = blockIdx.x, t = threadIdx.x;
  for (int p = t; p < 64*DM; p += 128){ xs[p/DM][p%DM] = xin[(size_t)b*64*DM + p]; }
  __syncthreads();
  if (t < 64){
    float s = 0.f;
    for (int m = 0; m < DM; m++) s += xs[t][m];
    float mn = s / (float)DM;
    float v = 0.f;
    for (int m = 0; m < DM; m++){ float d = xs[t][m] - mn; v += d*d; }
    mean_s[t] = mn; rstd_s[t] = rsqrtf(v / (float)DM + 1e-5f);
  }
  __syncthreads();
  if (t < DM){
    float gv = g[t], bv = bb[t];
    float acc = fcb[0];
    for (int l = 0; l < 64; l++){
      float xn = (xs[l][t] - mean_s[l])*rstd_s[l]*gv + bv;
      acc += xn * fcw[l];
    }
    out[b*DM + t] = acc;
  }
}

// ---------------- host launcher ----------------
extern "C" void kernel_launch(void* const* d_in, const int* in_sizes, int n_in,
                              void* d_out, int out_size, void* d_ws, size_t ws_size,
                              hipStream_t stream) {
  fp x_enc   = (fp)d_in[0];
  fp x_mark  = (fp)d_in[1];
  fp token_w = (fp)d_in[2];
  fp time_w  = (fp)d_in[3];
  fp time_b  = (fp)d_in[4];
  fp od_fc_w = (fp)d_in[5];
  fp od_bn_g = (fp)d_in[6];
  fp od_bn_b = (fp)d_in[7];
  fp od_ch_w = (fp)d_in[8];
  fp od_ch_b = (fp)d_in[9];
  fp od_fil_w= (fp)d_in[10];
  fp od_fil_b= (fp)d_in[11];
  fp od_sp_w = (fp)d_in[12];
  fp od_sp_b = (fp)d_in[13];
  fp od_ker_w= (fp)d_in[14];
  fp od_ker_b= (fp)d_in[15];
  fp od_wt   = (fp)d_in[16];
  fp q_w = (fp)d_in[17]; fp q_b = (fp)d_in[18];
  fp k_w = (fp)d_in[19]; fp k_b = (fp)d_in[20];
  fp v_w = (fp)d_in[21]; fp v_b = (fp)d_in[22];
  fp o_w = (fp)d_in[23]; fp o_b = (fp)d_in[24];
  fp f1w = (fp)d_in[25]; fp f1b = (fp)d_in[26];
  fp f2w = (fp)d_in[27]; fp f2b = (fp)d_in[28];
  fp ln1g= (fp)d_in[29]; fp ln1b= (fp)d_in[30];
  fp ln2g= (fp)d_in[31]; fp ln2b= (fp)d_in[32];
  fp cl_w= (fp)d_in[33]; fp cl_b= (fp)d_in[34];
  fp clbg= (fp)d_in[35]; fp clbb= (fp)d_in[36];
  fp elng= (fp)d_in[37]; fp elnb= (fp)d_in[38];
  fp fc_w= (fp)d_in[39]; fp fc_b= (fp)d_in[40];

  // ---- workspace layout (float units) ----
  const size_t OFF_IDX0 = 0;
  const size_t OFF_IDX1 = OFF_IDX0 + 3200;
  const size_t OFF_CH   = OFF_IDX1 + 1600;
  const size_t OFF_FIL  = OFF_CH  + (size_t)NB*DE;
  const size_t OFF_SP   = OFF_FIL + (size_t)NB*DE;
  const size_t OFF_KER  = OFF_SP  + (size_t)NB*4;
  const size_t OFF_VM   = OFF_KER + (size_t)NB*4;
  const size_t OFF_POS  = OFF_VM  + (size_t)NB*NH*DHd;
  const size_t OFF_UPD  = OFF_POS + (size_t)NB*NH*L0;
  const size_t OFF_STOP = OFF_UPD + (size_t)NB*NH*NTOP*DHd;
  const size_t OFF_WTS  = (OFF_STOP + (size_t)NB*NH*NTOP + 255) & ~(size_t)255;
  const size_t WTS_FLOATS = (2*262144 + 2*262144 + 2*49152 + 2*16384 + 49152 + 32768)/2 + 2*384;
  const size_t OFF_BIG  = (OFF_WTS + WTS_FLOATS + 255) & ~(size_t)255;
  const size_t SBUF     = (size_t)NB*DE*L0;
  const size_t TOTAL    = OFF_BIG + 4*SBUF;

  if (ws_size < TOTAL*sizeof(float)){
    hipLaunchKernelGGL(k_zero, dim3((out_size+255)/256), dim3(256), 0, stream,
                       (float*)d_out, out_size);
    return;
  }

  float* ws = (float*)d_ws;
  int* idx0 = (int*)(ws + OFF_IDX0);
  int* idx1 = (int*)(ws + OFF_IDX1);
  float* chv = ws + OFF_CH;
  float* filv= ws + OFF_FIL;
  float* spv = ws + OFF_SP;
  float* kerv= ws + OFF_KER;
  float* vme = ws + OFF_VM;
  int* posm  = (int*)(ws + OFF_POS);
  float* updb= ws + OFF_UPD;
  int* stopb = (int*)(ws + OFF_STOP);
  u16* w1tb  = (u16*)(ws + OFF_WTS);
  u16* w2tb  = w1tb + 2*262144;
  u16* wqkvb = w2tb + 2*262144;
  u16* wob   = wqkvb + 2*49152;
  u16* wdistb= wob + 2*16384;
  u16* wembb = wdistb + 49152;
  float* qkvbias = (float*)(wembb + 32768);

  float* X    = ws + OFF_BIG;
  float* QKV  = X + SBUF;
  float* emb  = QKV;
  float* xmid = QKV;
  float* ffno = QKV + SBUF;

  hipLaunchKernelGGL(k_idx, dim3(1), dim3(256), 0, stream, idx0, idx1);
  hipLaunchKernelGGL(k_wprep, dim3(4931), dim3(256), 0, stream,
                     token_w, cl_w, q_w, q_b, k_w, k_b, v_w, v_b, o_w, f1w, f2w,
                     wembb, wdistb, wqkvb, wob, w1tb, w2tb, qkvbias);
  hipLaunchKernelGGL(k_emb_mfma, dim3(NB), dim3(256), 0, stream,
                     x_enc, x_mark, wembb, time_w, time_b, emb);
  hipLaunchKernelGGL(k_scalars, dim3(NB), dim3(128), 0, stream,
                     emb, od_fc_w, od_bn_g, od_bn_b, od_ch_w, od_ch_b, od_fil_w, od_fil_b,
                     od_sp_w, od_sp_b, od_ker_w, od_ker_b, chv, filv, spv, kerv);
  hipLaunchKernelGGL(k_odconv_mfma, dim3(NB), dim3(256), 0, stream,
                     emb, od_wt, chv, filv, spv, kerv, X);

  // ----- layer 0 (L=128) -----
  hipLaunchKernelGGL(k_qkv_mfma, dim3(NB*L0/64), dim3(256), 0, stream,
                     X, wqkvb, qkvbias, QKV);
  hipLaunchKernelGGL(k_attn_sel, dim3(NB*NH/4), dim3(256), 0, stream,
                     QKV, idx0, L0, posm, stopb);
  hipLaunchKernelGGL(k_attn_pv, dim3(NB*NH/4), dim3(256), 0, stream,
                     QKV, stopb, L0, vme, updb);
  hipLaunchKernelGGL(k_oproj_mfma, dim3(NB*L0/64), dim3(256), 0, stream,
                     X, vme, posm, updb, wob, o_b, ln1g, ln1b, 0, 7, 127, xmid);
  hipLaunchKernelGGL(k_ffn_mfma, dim3(NB*L0/128), dim3(512), 0, stream,
                     xmid, w1tb, w2tb, f1b, f2b, ln2g, ln2b, 0, ffno);

  // ----- distil -----
  hipLaunchKernelGGL(k_distill_mfma, dim3(NB), dim3(256), 0, stream,
                     ffno, wdistb, cl_b, clbg, clbb, X);

  // ----- layer 1 (L=64) -----
  hipLaunchKernelGGL(k_qkv_mfma, dim3(NB*64/64), dim3(256), 0, stream,
                     X, wqkvb + 49152, qkvbias + 384, QKV);
  hipLaunchKernelGGL(k_attn_sel, dim3(NB*NH/4), dim3(256), 0, stream,
                     QKV, idx1, 64, posm, stopb);
  hipLaunchKernelGGL(k_attn_pv, dim3(NB*NH/4), dim3(256), 0, stream,
                     QKV, stopb, 64, vme, updb);
  hipLaunchKernelGGL(k_oproj_mfma, dim3(NB*64/64), dim3(256), 0, stream,
                     X, vme, posm, updb, wob + 16384, o_b, ln1g, ln1b, 1, 6, 63, xmid);
  hipLaunchKernelGGL(k_ffn_mfma, dim3(NB*64/128), dim3(512), 0, stream,
                     xmid, w1tb + 262144, w2tb + 262144, f1b, f2b, ln2g, ln2b, 1, ffno);

  hipLaunchKernelGGL(k_final, dim3(NB), dim3(128), 0, stream,
                     ffno, elng, elnb, fc_w, fc_b, (float*)d_out);
  (void)in_sizes; (void)n_in; (void)out_size; (void)ws_size;
}

// Round 16
// 763.683 us; speedup vs baseline: 1.0882x; 1.0882x over previous
//
#include <hip/hip_runtime.h>
#include <math.h>

// Problem dims
#define NB 256
#define DM 126       // D_MODEL
#define DE 128       // D_EMB
#define NH 6
#define DHd 21
#define DFF 2048
#define CIN 75
#define L0 128
#define NTOP 25

#ifndef IDX_MODE
#define IDX_MODE 0
#endif

typedef const float* fp;
typedef unsigned short u16;
typedef short s8v __attribute__((ext_vector_type(8)));
typedef float f4v __attribute__((ext_vector_type(4)));

__device__ __forceinline__ u16 f2bf(float x){
  unsigned u = __float_as_uint(x);
  unsigned r = (u + 0x7FFFu + ((u >> 16) & 1u)) >> 16;
  return (u16)r;
}
__device__ __forceinline__ float bf2f(u16 v){
  unsigned uu = ((unsigned)v) << 16;
  return __uint_as_float(uu);
}

__device__ __forceinline__ void gld_lds16(const u16* g, u16* l){
  __builtin_amdgcn_global_load_lds((const __attribute__((address_space(1))) unsigned int*)(const void*)g,
                                   (__attribute__((address_space(3))) unsigned int*)(void*)l,
                                   16, 0, 0);
}

__device__ __forceinline__ void tf2(unsigned k0, unsigned k1, unsigned x0, unsigned x1,
                                    unsigned &o0, unsigned &o1){
  unsigned ks2 = k0 ^ k1 ^ 0x1BD11BDAu;
  x0 += k0; x1 += k1;
  #define RR(r) { x0 += x1; x1 = (x1 << (r)) | (x1 >> (32 - (r))); x1 ^= x0; }
  RR(13) RR(15) RR(26) RR(6)
  x0 += k1;  x1 += ks2 + 1u;
  RR(17) RR(29) RR(16) RR(24)
  x0 += ks2; x1 += k0 + 2u;
  RR(13) RR(15) RR(26) RR(6)
  x0 += k0;  x1 += k1 + 3u;
  RR(17) RR(29) RR(16) RR(24)
  x0 += k1;  x1 += ks2 + 4u;
  RR(13) RR(15) RR(26) RR(6)
  x0 += ks2; x1 += k0 + 5u;
  #undef RR
  o0 = x0; o1 = x1;
}

// ---------------- fallback: zero output (ws too small diagnostic) ----------------
__global__ __launch_bounds__(256) void k_zero(float* out, int n){
  int i = blockIdx.x*256 + threadIdx.x;
  if (i < n) out[i] = 0.f;
}

// ---------------- idx precompute ----------------
__global__ __launch_bounds__(256) void k_idx(int* idx0, int* idx1){
  int tid = threadIdx.x;
  unsigned a0,a1,c0,c1;
  tf2(0u,42u, 0u,0u, a0,a1);
  tf2(0u,42u, 0u,1u, c0,c1);
  for (int f = tid; f < 3200; f += 256){
    unsigned y0,y1;
#if IDX_MODE==0
    tf2(a0,a1, 0u, (unsigned)(3200+f), y0,y1); idx0[f] = (int)(y1 & 127u);
#elif IDX_MODE==1
    tf2(a0,a1, 0u, (unsigned)(3200+f), y0,y1); idx0[f] = (int)(y0 & 127u);
#elif IDX_MODE==2
    tf2(a0,a1, (unsigned)f, (unsigned)(3200+f), y0,y1); idx0[f] = (int)(y1 & 127u);
#else
    tf2(a0,a1, (unsigned)f, (unsigned)(3200+f), y0,y1); idx0[f] = (int)(y0 & 127u);
#endif
  }
  for (int f = tid; f < 1600; f += 256){
    unsigned y0,y1;
#if IDX_MODE==0
    tf2(c0,c1, 0u, (unsigned)(1600+f), y0,y1); idx1[f] = (int)(y1 & 63u);
#elif IDX_MODE==1
    tf2(c0,c1, 0u, (unsigned)(1600+f), y0,y1); idx1[f] = (int)(y0 & 63u);
#elif IDX_MODE==2
    tf2(c0,c1, (unsigned)f, (unsigned)(1600+f), y0,y1); idx1[f] = (int)(y1 & 63u);
#else
    tf2(c0,c1, (unsigned)f, (unsigned)(1600+f), y0,y1); idx1[f] = (int)(y0 & 63u);
#endif
  }
}

// ---------------- unified weight prep (both layers) ----------------
__global__ __launch_bounds__(256) void k_wprep(fp token_w, fp clw,
                                               fp qw, fp qb, fp kw, fp kb, fp vw, fp vb, fp ow,
                                               fp f1w, fp f2w,
                                               u16* wemb, u16* wdist, u16* wqkv, u16* wo,
                                               u16* w1t, u16* w2t, float* qbias){
  int i = blockIdx.x*256 + threadIdx.x;
  if (i < 32768){
    int n = i >> 8, k = i & 255;
    float v = 0.f;
    if (k < 225){ int q = k/75, c = k - q*75; v = token_w[(size_t)n*225 + c*3 + q]; }
    wemb[i] = f2bf(v);
    return;
  }
  i -= 32768;
  if (i < 49152){
    int n = i / 384, k = i - n*384;
    float v = 0.f;
    if (n < DM && k < 378){ int q = k/126, ci = k - q*126; v = clw[((size_t)n*DM + ci)*3 + q]; }
    wdist[i] = f2bf(v);
    return;
  }
  i -= 49152;
  if (i < 2*49152){
    int layer = i / 49152, jj = i - layer*49152;
    int n = jj >> 7, k = jj & 127;
    int sec = n >> 7, nn = n & 127;
    const float* w = (sec == 0) ? qw : ((sec == 1) ? kw : vw);
    float v = (nn < DM && k < DM) ? w[((size_t)layer*DM + k)*DM + nn] : 0.f;
    wqkv[(size_t)layer*49152 + jj] = f2bf(v);
    return;
  }
  i -= 2*49152;
  if (i < 2*16384){
    int layer = i / 16384, jj = i - layer*16384;
    int n = jj >> 7, k = jj & 127;
    float v = (n < DM && k < DM) ? ow[(size_t)layer*DM*DM + k*DM + n] : 0.f;
    wo[(size_t)layer*16384 + jj] = f2bf(v);
    return;
  }
  i -= 2*16384;
  if (i < 2*262144){
    int layer = i / 262144, jj = i - layer*262144;
    int n = jj >> 7, k = jj & 127;
    float v = (k < DM) ? f1w[((size_t)layer*DM + k)*DFF + n] : 0.f;
    w1t[(size_t)layer*262144 + jj] = f2bf(v);
    return;
  }
  i -= 2*262144;
  if (i < 2*262144){
    int layer = i / 262144, jj = i - layer*262144;
    int n = jj >> 11, f = jj & 2047;
    float v = (n < DM) ? f2w[((size_t)layer*DFF + f)*DM + n] : 0.f;
    w2t[(size_t)layer*262144 + jj] = f2bf(v);
    return;
  }
  i -= 2*262144;
  if (i < 768){
    int layer = i / 384, n = i - layer*384;
    int sec = n >> 7, nn = n & 127;
    const float* bp = (sec == 0) ? qb : ((sec == 1) ? kb : vb);
    qbias[(size_t)layer*384 + n] = (nn < DM) ? bp[layer*DM + nn] : 0.f;
  }
}

// ---------------- MFMA token-embed: conv(K=225) + pos + time, out emb[b][l][e] ----------------
// staging: read each x_enc element ONCE (float4), scatter to its 3 conv-tap LDS slots
__global__ __launch_bounds__(256) void k_emb_mfma(fp x_enc, fp x_mark, const u16* wemb,
                                                  fp time_w, fp time_b, float* emb){
  __shared__ __align__(16) u16 sA[128*264];
  const int tid = threadIdx.x;
  const int wave = tid >> 6, lane = tid & 63, quad = lane >> 4, l15 = lane & 15;
  const int b = blockIdx.x;
  {
    const float4* xb = reinterpret_cast<const float4*>(x_enc + (size_t)b*L0*CIN);
    for (int p4 = tid; p4 < (L0*CIN)/4; p4 += 256){   // 2400 float4s
      float4 v4 = xb[p4];
      float vv[4] = {v4.x, v4.y, v4.z, v4.w};
      int e0 = p4*4;
      #pragma unroll
      for (int j = 0; j < 4; j++){
        int e = e0 + j;
        int sr = e / CIN, c = e - sr*CIN;
        u16 bv = f2bf(vv[j]);
        sA[((sr + 1) & 127)*264 + c] = bv;          // q=0 tap
        sA[sr*264 + 75 + c] = bv;                   // q=1 tap
        sA[((sr + 127) & 127)*264 + 150 + c] = bv;  // q=2 tap
      }
    }
    for (int p = tid; p < 128*31; p += 256){          // zero pad kk in [225,256)
      int row = p / 31, c2 = p - row*31;
      sA[row*264 + 225 + c2] = 0;
    }
  }
  __syncthreads();
  const f4v z4 = {0.f,0.f,0.f,0.f};
  f4v acc[2][8];
  #pragma unroll
  for (int m = 0; m < 2; m++)
    #pragma unroll
    for (int t = 0; t < 8; t++) acc[m][t] = z4;
  const int mBase = wave * 32;
  for (int ks = 0; ks < 8; ks++){
    s8v a0 = *reinterpret_cast<const s8v*>(sA + (mBase + l15)*264 + ks*32 + quad*8);
    s8v a1 = *reinterpret_cast<const s8v*>(sA + (mBase + 16 + l15)*264 + ks*32 + quad*8);
    const u16* wb = wemb + (size_t)l15*256 + ks*32 + quad*8;
    #pragma unroll
    for (int t = 0; t < 8; t++){
      s8v bfr = *reinterpret_cast<const s8v*>(wb + (size_t)t*16*256);
      acc[0][t] = __builtin_amdgcn_mfma_f32_16x16x32_bf16(a0, bfr, acc[0][t], 0, 0, 0);
      acc[1][t] = __builtin_amdgcn_mfma_f32_16x16x32_bf16(a1, bfr, acc[1][t], 0, 0, 0);
    }
  }
  // epilogue: hoisted per-col constants + per-row x_mark loads
  float divc[8], tw0c[8], tw1c[8], tw2c[8], tbc[8];
  #pragma unroll
  for (int t = 0; t < 8; t++){
    int col = t*16 + l15;
    int i2 = col >> 1;
    divc[t] = __expf((float)(2*i2) * (-9.210340371976184f / 128.f));
    tw0c[t] = time_w[col]; tw1c[t] = time_w[128 + col]; tw2c[t] = time_w[256 + col];
    tbc[t] = time_b[col];
  }
  #pragma unroll
  for (int m = 0; m < 2; m++){
    #pragma unroll
    for (int r = 0; r < 4; r++){
      int row = mBase + m*16 + quad*4 + r;
      const float* mk = x_mark + ((size_t)b*L0 + row)*3;
      float m0v = mk[0], m1v = mk[1], m2v = mk[2];
      float* erow = emb + ((size_t)b*L0 + row)*DE;
      #pragma unroll
      for (int t = 0; t < 8; t++){
        int col = t*16 + l15;
        float ang = (float)row * divc[t];
        float pe = (col & 1) ? cosf(ang) : sinf(ang);
        float tm = m0v*tw0c[t] + m1v*tw1c[t] + m2v*tw2c[t] + tbc[t];
        erow[col] = acc[m][t][r] + pe + tm;
      }
    }
  }
}

// ---------------- per-batch attention scalars (emb layout [b][l][e]) ----------------
__global__ __launch_bounds__(128) void k_scalars(const float* emb, fp fcw, fp bng, fp bnb,
                                                 fp chw, fp chb, fp filw, fp filb,
                                                 fp spw, fp spb, fp kerw, fp kerb,
                                                 float* ch, float* fil, float* sp, float* ker){
  __shared__ float gap[DE];
  __shared__ float a[16];
  int b = blockIdx.x, t = threadIdx.x;
  float s = 0.f;
  for (int l = 0; l < L0; l++) s += emb[((size_t)b*L0 + l)*DE + t];
  gap[t] = s / (float)L0;
  __syncthreads();
  if (t < 16){
    float acc = 0.f;
    for (int e = 0; e < DE; e++) acc += gap[e]*fcw[e*16 + t];
    acc = acc * (bng[t] / sqrtf(1.f + 1e-5f)) + bnb[t];
    a[t] = fmaxf(acc, 0.f);
  }
  __syncthreads();
  float accc = 0.f, accf = 0.f;
  for (int c = 0; c < 16; c++){ accc += a[c]*chw[c*DE + t]; accf += a[c]*filw[c*DE + t]; }
  ch[b*DE + t]  = 1.f/(1.f + expf(-(accc + chb[t])));
  fil[b*DE + t] = 1.f/(1.f + expf(-(accf + filb[t])));
  if (t < 3){
    float acc = 0.f;
    for (int c = 0; c < 16; c++) acc += a[c]*spw[c*3 + t];
    sp[b*4 + t] = 1.f/(1.f + expf(-(acc + spb[t])));
  }
  if (t == 0){
    float v[4]; float mx = -1e30f;
    for (int n = 0; n < 4; n++){
      float acc = 0.f;
      for (int c = 0; c < 16; c++) acc += a[c]*kerw[c*4 + n];
      v[n] = acc + kerb[n]; mx = fmaxf(mx, v[n]);
    }
    float ss = 0.f;
    for (int n = 0; n < 4; n++){ v[n] = expf(v[n]-mx); ss += v[n]; }
    for (int n = 0; n < 4; n++) ker[b*4 + n] = v[n]/ss;
  }
}

// ---------------- MFMA ODConv ----------------
__global__ __launch_bounds__(256) void k_odconv_mfma(const float* emb, fp odw,
                                                     const float* ch, const float* fil,
                                                     const float* sp, const float* ker, float* xout){
  __shared__ __align__(16) u16 sXT[130*136];
  __shared__ __align__(16) u16 sW[3*128*136];
  const int tid = threadIdx.x;
  const int wave = tid >> 6, lane = tid & 63, quad = lane >> 4, l15 = lane & 15;
  const int b = blockIdx.x;
  for (int p = tid; p < 130*128; p += 256){
    int l = p >> 7, i = p & 127;
    float v = 0.f;
    if (l < 128) v = emb[((size_t)b*L0 + l)*DE + i] * ch[b*DE + i];
    sXT[l*136 + i] = f2bf(v);
  }
  float kr0 = ker[b*4+0], kr1 = ker[b*4+1], kr2 = ker[b*4+2], kr3 = ker[b*4+3];
  float spv[3]; spv[0] = sp[b*4+0]; spv[1] = sp[b*4+1]; spv[2] = sp[b*4+2];
  const float4* od4 = (const float4*)odw;
  for (int p4 = tid; p4 < 128*384/4; p4 += 256){
    float4 w0 = od4[p4];
    float4 w1 = od4[12288 + p4];
    float4 w2 = od4[24576 + p4];
    float4 w3 = od4[36864 + p4];
    float vv[4] = { kr0*w0.x + kr1*w1.x + kr2*w2.x + kr3*w3.x,
                    kr0*w0.y + kr1*w1.y + kr2*w2.y + kr3*w3.y,
                    kr0*w0.z + kr1*w1.z + kr2*w2.z + kr3*w3.z,
                    kr0*w0.w + kr1*w1.w + kr2*w2.w + kr3*w3.w };
    int e0 = p4*4;
    #pragma unroll
    for (int j = 0; j < 4; j++){
      int e = e0 + j;
      int o = e / 384, rem = e - o*384;
      int i = rem / 3, q = rem - i*3;
      sW[(q*128 + o)*136 + i] = f2bf(vv[j] * spv[q]);
    }
  }
  __syncthreads();
  const f4v z4 = {0.f,0.f,0.f,0.f};
  f4v acc[2][8];
  #pragma unroll
  for (int m = 0; m < 2; m++)
    #pragma unroll
    for (int t = 0; t < 8; t++) acc[m][t] = z4;
  const int mBase = wave * 32;
  for (int q = 0; q < 3; q++){
    const u16* wq = sW + q*128*136;
    #pragma unroll
    for (int ks = 0; ks < 4; ks++){
      s8v a0 = *reinterpret_cast<const s8v*>(wq + (mBase + l15)*136 + ks*32 + quad*8);
      s8v a1 = *reinterpret_cast<const s8v*>(wq + (mBase + 16 + l15)*136 + ks*32 + quad*8);
      #pragma unroll
      for (int t = 0; t < 8; t++){
        s8v bfr = *reinterpret_cast<const s8v*>(sXT + (t*16 + l15 + q)*136 + ks*32 + quad*8);
        acc[0][t] = __builtin_amdgcn_mfma_f32_16x16x32_bf16(a0, bfr, acc[0][t], 0, 0, 0);
        acc[1][t] = __builtin_amdgcn_mfma_f32_16x16x32_bf16(a1, bfr, acc[1][t], 0, 0, 0);
      }
    }
  }
  #pragma unroll
  for (int t = 0; t < 8; t++){
    int tt = t*16 + l15;
    if (tt < DM){
      #pragma unroll
      for (int m = 0; m < 2; m++){
        #pragma unroll
        for (int r = 0; r < 4; r++){
          int o = mBase + m*16 + quad*4 + r;
          xout[((size_t)b*DE + o)*DM + tt] = fil[b*DE + o] * acc[m][t][r];
        }
      }
    }
  }
}

// ---------------- fused QKV GEMM: qkv[M][384] ----------------
__global__ __launch_bounds__(256) void k_qkv_mfma(const float* xin, const u16* wqkv,
                                                  const float* qkvb, float* qkv){
  __shared__ __align__(16) u16 sX[64*136];
  const int tid = threadIdx.x;
  const int wave = tid >> 6, lane = tid & 63, quad = lane >> 4, l15 = lane & 15;
  const size_t rows0 = (size_t)blockIdx.x * 64;
  for (int p = tid; p < 64*128; p += 256){
    int r = p >> 7, c = p & 127;
    float v = (c < DM) ? xin[(rows0 + r)*DM + c] : 0.f;
    sX[r*136 + c] = f2bf(v);
  }
  __syncthreads();
  const f4v z4 = {0.f,0.f,0.f,0.f};
  f4v acc[24];
  #pragma unroll
  for (int t = 0; t < 24; t++) acc[t] = z4;
  const int m0 = wave * 16;
  #pragma unroll
  for (int ks = 0; ks < 4; ks++){
    s8v a = *reinterpret_cast<const s8v*>(sX + (m0 + l15)*136 + ks*32 + quad*8);
    const u16* wb = wqkv + (size_t)l15*128 + ks*32 + quad*8;
    #pragma unroll
    for (int t = 0; t < 24; t++){
      s8v b = *reinterpret_cast<const s8v*>(wb + (size_t)t*16*128);
      acc[t] = __builtin_amdgcn_mfma_f32_16x16x32_bf16(a, b, acc[t], 0, 0, 0);
    }
  }
  #pragma unroll
  for (int t = 0; t < 24; t++){
    int col = t*16 + l15;
    float bv = qkvb[col];
    #pragma unroll
    for (int r = 0; r < 4; r++){
      int row = m0 + quad*4 + r;
      qkv[(rows0 + row)*384 + col] = acc[t][r] + bv;
    }
  }
}

// ---------------- attention phase 1: exact M + top-k selection (one wave per bh) ----------------
__global__ __launch_bounds__(256) void k_attn_sel(const float* qkv, const int* idx, int L,
                                                  int* posmap, int* stopb){
  __shared__ float smem[4*2816];
  const int tid = threadIdx.x;
  const int wave = tid >> 6, lane = tid & 63;
  const int bh = blockIdx.x*4 + wave;
  const int b = bh / NH, h = bh - b*NH;
  float* sK = smem + wave*2816;
  float* sM = sK + 2688;
  const float* qbase = qkv + (size_t)(b*L)*384 + h*DHd;
  for (int p = lane; p < L*DHd; p += 64){
    int l = p / DHd, d = p - l*DHd;
    sK[p] = qbase[(size_t)l*384 + 128 + d];
  }
  posmap[bh*L0 + lane] = -1;
  if (L == 128) posmap[bh*L0 + 64 + lane] = -1;
  __syncthreads();
  int nr = (L == 128) ? 2 : 1;
  for (int rr = 0; rr < nr; rr++){
    int l = lane + rr*64;
    const float* qg = qbase + (size_t)l*384;
    float qr[DHd];
    #pragma unroll
    for (int d = 0; d < DHd; d++) qr[d] = qg[d];
    float mx = -1e30f, sm = 0.f;
    #pragma unroll
    for (int u = 0; u < NTOP; u++){
      int kk = idx[l*NTOP + u];
      const float* kp = sK + kk*DHd;
      float acc = 0.f;
      #pragma unroll
      for (int d = 0; d < DHd; d++) acc += qr[d]*kp[d];
      mx = fmaxf(mx, acc); sm += acc;
    }
    sM[l] = mx - sm/(float)L;
  }
  for (int it = 0; it < NTOP; it++){
    float bv = sM[lane]; int bi = lane;
    if (L == 128){
      float v1 = sM[lane + 64];
      if (v1 > bv){ bv = v1; bi = lane + 64; }
    }
    #pragma unroll
    for (int off = 32; off > 0; off >>= 1){
      float ov = __shfl_xor(bv, off);
      int   oi = __shfl_xor(bi, off);
      if (ov > bv || (ov == bv && oi < bi)){ bv = ov; bi = oi; }
    }
    if (lane == 0){
      sM[bi] = -1e30f;
      posmap[bh*L0 + bi] = it;
      stopb[bh*NTOP + it] = bi;
    }
  }
}

// ---------------- attention phase 2: softmax(QselK^T)V via MFMA, LDS = P only ----------------
#define PV_SLICE 4352
__global__ __launch_bounds__(256) void k_attn_pv(const float* qkv, const int* stopb, int L,
                                                 float* vmean, float* upd){
  __shared__ __align__(16) u16 smem[4*PV_SLICE];
  const int tid = threadIdx.x;
  const int wave = tid >> 6, lane = tid & 63, quad = lane >> 4, l15 = lane & 15;
  const int bh = blockIdx.x*4 + wave;
  const int b = bh / NH, h = bh - b*NH;
  u16* sPb = smem + wave*PV_SLICE;
  const float* qbase = qkv + (size_t)(b*L)*384 + h*DHd;
  const f4v z4 = {0.f,0.f,0.f,0.f};
  const int ntn = L >> 4;
  const int d0 = quad*8;

  f4v sc[2][8];
  #pragma unroll
  for (int mt = 0; mt < 2; mt++){
    int uu = mt*16 + l15; if (uu >= NTOP) uu = 0;
    int r = stopb[bh*NTOP + uu];
    const float* qp = qbase + (size_t)r*384 + d0;
    s8v a;
    #pragma unroll
    for (int j = 0; j < 8; j++) a[j] = (short)f2bf(qp[j]);
    for (int nt = 0; nt < ntn; nt++){
      const float* kp = qbase + 128 + (size_t)(nt*16 + l15)*384 + d0;
      s8v bb;
      #pragma unroll
      for (int j = 0; j < 8; j++) bb[j] = (d0 + j < DHd) ? (short)f2bf(kp[j]) : (short)0;
      sc[mt][nt] = __builtin_amdgcn_mfma_f32_16x16x32_bf16(a, bb, z4, 0, 0, 0);
    }
  }
  const float inv21 = 0.21821789023599236f;   // 1/sqrt(21)
  #pragma unroll
  for (int mt = 0; mt < 2; mt++){
    #pragma unroll
    for (int r4 = 0; r4 < 4; r4++){
      float mx = -1e30f;
      for (int nt = 0; nt < ntn; nt++) mx = fmaxf(mx, sc[mt][nt][r4]*inv21);
      #pragma unroll
      for (int off = 1; off < 16; off <<= 1) mx = fmaxf(mx, __shfl_xor(mx, off));
      float e[8]; float ss = 0.f;
      for (int nt = 0; nt < ntn; nt++){ e[nt] = expf(sc[mt][nt][r4]*inv21 - mx); ss += e[nt]; }
      #pragma unroll
      for (int off = 1; off < 16; off <<= 1) ss += __shfl_xor(ss, off);
      float dn = 1.f / ss;
      int u = mt*16 + quad*4 + r4;
      for (int nt = 0; nt < ntn; nt++)
        sPb[u*136 + nt*16 + l15] = f2bf(e[nt]*dn);
    }
  }
  {
    u16 invL = f2bf(1.f/(float)L);
    for (int c = lane; c < L; c += 64) sPb[25*136 + c] = invL;
  }
  f4v pv[2][2];
  pv[0][0]=z4; pv[0][1]=z4; pv[1][0]=z4; pv[1][1]=z4;
  int kSteps = L >> 5;
  for (int ks = 0; ks < kSteps; ks++){
    #pragma unroll
    for (int nt = 0; nt < 2; nt++){
      const float* vp = qbase + 256 + (size_t)(ks*32 + d0)*384 + nt*16 + l15;
      s8v bb;
      #pragma unroll
      for (int j = 0; j < 8; j++) bb[j] = (short)f2bf(vp[(size_t)j*384]);
      #pragma unroll
      for (int mt = 0; mt < 2; mt++){
        s8v a = *reinterpret_cast<const s8v*>(sPb + (mt*16 + l15)*136 + ks*32 + d0);
        pv[mt][nt] = __builtin_amdgcn_mfma_f32_16x16x32_bf16(a, bb, pv[mt][nt], 0, 0, 0);
      }
    }
  }
  #pragma unroll
  for (int mt = 0; mt < 2; mt++){
    #pragma unroll
    for (int nt = 0; nt < 2; nt++){
      #pragma unroll
      for (int r4 = 0; r4 < 4; r4++){
        int u = mt*16 + quad*4 + r4;
        int d = nt*16 + l15;
        if (d < DHd){
          if (u < NTOP)       upd[((size_t)bh*NTOP + u)*DHd + d] = pv[mt][nt][r4];
          else if (u == NTOP) vmean[bh*DHd + d] = pv[mt][nt][r4];
        }
      }
    }
  }
}

// ---------------- MFMA O-proj + residual + LN1 (64 rows / block) ----------------
__global__ __launch_bounds__(256) void k_oproj_mfma(const float* xin, const float* vmean,
                                                    const int* posmap, const float* upd,
                                                    const u16* wo, fp ob, fp g, fp bb,
                                                    int layer, int lshift, int lmask, float* xmid){
  __shared__ __align__(16) float sOf[64*129];
  __shared__ float prs[128];
  __shared__ float smean[64], srstd[64];
  u16* sX = reinterpret_cast<u16*>(sOf);
  const int tid = threadIdx.x;
  const int wave = tid >> 6, lane = tid & 63, quad = lane >> 4, l15 = lane & 15;
  const int m0 = wave * 16;
  const size_t rows0 = (size_t)blockIdx.x * 64;
  for (int p = tid; p < 64*128; p += 256){
    int r = p >> 7, c = p & 127;
    int gr = (int)rows0 + r, b = gr >> lshift, l = gr & lmask;
    float v = 0.f;
    if (c < DM){
      int h = c / DHd, d = c - h*DHd;
      int bh = b*NH + h;
      int pos = posmap[bh*L0 + l];
      v = (pos >= 0) ? upd[((size_t)bh*NTOP + pos)*DHd + d] : vmean[bh*DHd + d];
    }
    sX[r*136 + c] = f2bf(v);
  }
  __syncthreads();
  const f4v z4 = {0.f,0.f,0.f,0.f};
  f4v acc[8];
  #pragma unroll
  for (int t = 0; t < 8; t++) acc[t] = z4;
  #pragma unroll
  for (int ks = 0; ks < 4; ks++){
    s8v a = *reinterpret_cast<const s8v*>(sX + (m0 + l15)*136 + ks*32 + quad*8);
    const u16* wb = wo + (size_t)l15*128 + ks*32 + quad*8;
    #pragma unroll
    for (int t = 0; t < 8; t++){
      s8v b = *reinterpret_cast<const s8v*>(wb + (size_t)t*16*128);
      acc[t] = __builtin_amdgcn_mfma_f32_16x16x32_bf16(a, b, acc[t], 0, 0, 0);
    }
  }
  __syncthreads();
  #pragma unroll
  for (int t = 0; t < 8; t++){
    int col = t*16 + l15;
    #pragma unroll
    for (int r = 0; r < 4; r++){
      sOf[(m0 + quad*4 + r)*129 + col] = acc[t][r];
    }
  }
  __syncthreads();
  const float* obl = ob + (size_t)layer*DM;
  for (int p = tid; p < 64*DM; p += 256){
    int r = p / DM, c = p - r*DM;
    sOf[r*129 + c] += xin[(rows0 + r)*DM + c] + obl[c];
  }
  __syncthreads();
  if (tid < 128){
    int row = tid >> 1, half = tid & 1;
    float s = 0.f;
    for (int c = half*63; c < half*63 + 63; c++) s += sOf[row*129 + c];
    prs[tid] = s;
  }
  __syncthreads();
  if (tid < 128 && (tid & 1) == 0) smean[tid>>1] = (prs[tid] + prs[tid+1]) / (float)DM;
  __syncthreads();
  if (tid < 128){
    int row = tid >> 1, half = tid & 1;
    float mn = smean[row];
    float s = 0.f;
    for (int c = half*63; c < half*63 + 63; c++){ float d = sOf[row*129 + c] - mn; s += d*d; }
    prs[tid] = s;
  }
  __syncthreads();
  if (tid < 128 && (tid & 1) == 0) srstd[tid>>1] = rsqrtf((prs[tid] + prs[tid+1])/(float)DM + 1e-5f);
  __syncthreads();
  const float* gl = g  + (size_t)layer*DM;
  const float* bl = bb + (size_t)layer*DM;
  for (int p = tid; p < 64*DM; p += 256){
    int r = p / DM, c = p - r*DM;
    xmid[(rows0 + r)*DM + c] = (sOf[r*129 + c] - smean[r])*srstd[r]*gl[c] + bl[c];
  }
}

// fast GELU: tanh form, x*t/(t+1) with t=exp(1.5957691x + 0.0713548x^3)
__device__ __forceinline__ float gelu_fast(float x){
  float x2 = x*x;
  float u = x * __builtin_fmaf(0.07135481f, x2, 1.5957691f);
  u = fminf(u, 85.f);
  float t = __expf(u);
  return x * t * __builtin_amdgcn_rcpf(t + 1.f);
}

// ---------------- FFN variant A: 512 thr / 128 rows (for L=128 layer) ----------------
#define FFN_SMEM_U16 (9216 + 4*8192)

__device__ __forceinline__ void stage_w1_512(const u16* w1t, int j, u16* buf, int tid){
  #pragma unroll
  for (int r = 0; r < 2; r++){
    int p = r*512 + tid;
    int n = p >> 4, c = p & 15;
    int cg = c ^ (n & 7);
    const u16* g = w1t + (((size_t)(j*64 + n)) << 7) + cg*8;
    u16* l = buf + (size_t)((p >> 6) << 6)*8;
    gld_lds16(g, l);
  }
}
__device__ __forceinline__ void stage_w2_512(const u16* w2t, int j, u16* buf, int tid){
  #pragma unroll
  for (int r = 0; r < 2; r++){
    int p = r*512 + tid;
    int n = p >> 3, c = p & 7;
    int cg = c ^ (n & 7);
    const u16* g = w2t + (size_t)n*2048 + j*64 + cg*8;
    u16* l = buf + (size_t)((p >> 6) << 6)*8;
    gld_lds16(g, l);
  }
}

__global__ __launch_bounds__(512) void k_ffn_mfma(const float* xmid, const u16* w1t, const u16* w2t,
                                                  fp b1, fp b2w, fp g, fp bb, int layer, float* xout){
  __shared__ __align__(16) u16 smem[FFN_SMEM_U16];
  __shared__ float prs[256];
  __shared__ float smean[128], srstd[128];
  u16* wA0 = smem + 9216;
  u16* wA1 = wA0 + 8192;
  u16* wB0 = wA1 + 8192;
  u16* wB1 = wB0 + 8192;
  const int tid  = threadIdx.x;
  const int wave = tid >> 6, lane = tid & 63, quad = lane >> 4, l15 = lane & 15;
  const int m0 = wave * 16;
  u16* sYw = smem + wave*1152;
  const size_t rows0 = (size_t)blockIdx.x * 128;

  s8v aX[4];
  {
    const float* xr = xmid + (rows0 + m0 + l15)*(size_t)DM;
    #pragma unroll
    for (int ks = 0; ks < 4; ks++){
      #pragma unroll
      for (int j = 0; j < 8; j++){
        int c = ks*32 + quad*8 + j;
        float v = (c < DM) ? xr[c] : 0.f;
        aX[ks][j] = (short)f2bf(v);
      }
    }
  }
  stage_w1_512(w1t, 0, wA0, tid);
  stage_w2_512(w2t, 0, wB0, tid);
  __syncthreads();

  const float* b1l = b1 + (size_t)layer*DFF;
  const f4v z4 = {0.f, 0.f, 0.f, 0.f};
  f4v acc2[8];
  #pragma unroll
  for (int t = 0; t < 8; t++) acc2[t] = z4;

  for (int j = 0; j < 32; j++){
    u16* wAcur = (j & 1) ? wA1 : wA0;
    u16* wAnxt = (j & 1) ? wA0 : wA1;
    u16* wBcur = (j & 1) ? wB1 : wB0;
    u16* wBnxt = (j & 1) ? wB0 : wB1;
    if (j < 31){
      stage_w1_512(w1t, j+1, wAnxt, tid);
      stage_w2_512(w2t, j+1, wBnxt, tid);
    }
    f4v acc1[4];
    #pragma unroll
    for (int t = 0; t < 4; t++) acc1[t] = z4;
    #pragma unroll
    for (int ks = 0; ks < 4; ks++){
      #pragma unroll
      for (int t = 0; t < 4; t++){
        int nloc = t*16 + l15;
        int cg = (ks*4 + quad) ^ (nloc & 7);
        s8v b = *reinterpret_cast<const s8v*>(wAcur + nloc*128 + cg*8);
        acc1[t] = __builtin_amdgcn_mfma_f32_16x16x32_bf16(aX[ks], b, acc1[t], 0, 0, 0);
      }
    }
    #pragma unroll
    for (int t = 0; t < 4; t++){
      float bv = b1l[j*64 + t*16 + l15];
      #pragma unroll
      for (int r = 0; r < 4; r++){
        float v = gelu_fast(acc1[t][r] + bv);
        sYw[(quad*4 + r)*72 + t*16 + l15] = f2bf(v);
      }
    }
    #pragma unroll
    for (int ks = 0; ks < 2; ks++){
      s8v a2 = *reinterpret_cast<const s8v*>(sYw + l15*72 + ks*32 + quad*8);
      #pragma unroll
      for (int t = 0; t < 8; t++){
        int nloc = t*16 + l15;
        int cg = (ks*4 + quad) ^ (nloc & 7);
        s8v b = *reinterpret_cast<const s8v*>(wBcur + nloc*64 + cg*8);
        acc2[t] = __builtin_amdgcn_mfma_f32_16x16x32_bf16(a2, b, acc2[t], 0, 0, 0);
      }
    }
    __syncthreads();
  }

  float* sO = reinterpret_cast<float*>(smem);
  #pragma unroll
  for (int t = 0; t < 8; t++){
    int col = t*16 + l15;
    #pragma unroll
    for (int r = 0; r < 4; r++){
      sO[(m0 + quad*4 + r)*129 + col] = acc2[t][r];
    }
  }
  __syncthreads();
  const float* b2l = b2w + (size_t)layer*DM;
  for (int p = tid; p < 128*DM; p += 512){
    int r = p / DM, c = p - r*DM;
    sO[r*129 + c] += b2l[c] + xmid[(rows0 + r)*DM + c];
  }
  __syncthreads();
  if (tid < 256){
    int row = tid >> 1, half = tid & 1;
    float s = 0.f;
    for (int c = half*63; c < half*63 + 63; c++) s += sO[row*129 + c];
    prs[tid] = s;
  }
  __syncthreads();
  if (tid < 256 && (tid & 1) == 0) smean[tid>>1] = (prs[tid] + prs[tid+1]) / (float)DM;
  __syncthreads();
  if (tid < 256){
    int row = tid >> 1, half = tid & 1;
    float mn = smean[row];
    float s = 0.f;
    for (int c = half*63; c < half*63 + 63; c++){ float d = sO[row*129 + c] - mn; s += d*d; }
    prs[tid] = s;
  }
  __syncthreads();
  if (tid < 256 && (tid & 1) == 0) srstd[tid>>1] = rsqrtf((prs[tid] + prs[tid+1])/(float)DM + 1e-5f);
  __syncthreads();
  const float* gl = g  + (size_t)layer*DM;
  const float* bl = bb + (size_t)layer*DM;
  for (int p = tid; p < 128*DM; p += 512){
    int r = p / DM, c = p - r*DM;
    xout[(rows0 + r)*DM + c] = (sO[r*129 + c] - smean[r])*srstd[r]*gl[c] + bl[c];
  }
}

// ---------------- FFN variant B: 256 thr / 64 rows (for L=64 layer, 256 blocks) ----------------
#define FFN_SMEM_U16_256 (4608 + 4*8192)

__device__ __forceinline__ void stage_w1_256(const u16* w1t, int j, u16* buf, int wave, int lane){
  #pragma unroll
  for (int r = 0; r < 4; r++){
    int p = r*256 + wave*64 + lane;
    int n = p >> 4, c = p & 15;
    int cg = c ^ (n & 7);
    const u16* g = w1t + (((size_t)(j*64 + n)) << 7) + cg*8;
    u16* l = buf + (size_t)(r*256 + wave*64)*8;
    gld_lds16(g, l);
  }
}
__device__ __forceinline__ void stage_w2_256(const u16* w2t, int j, u16* buf, int wave, int lane){
  #pragma unroll
  for (int r = 0; r < 4; r++){
    int p = r*256 + wave*64 + lane;
    int n = p >> 3, c = p & 7;
    int cg = c ^ (n & 7);
    const u16* g = w2t + (size_t)n*2048 + j*64 + cg*8;
    u16* l = buf + (size_t)(r*256 + wave*64)*8;
    gld_lds16(g, l);
  }
}

__global__ __launch_bounds__(256) void k_ffn_mfma256(const float* xmid, const u16* w1t, const u16* w2t,
                                                     fp b1, fp b2w, fp g, fp bb, int layer, float* xout){
  __shared__ __align__(16) u16 smem[FFN_SMEM_U16_256];
  __shared__ float prs[128];
  __shared__ float smean[64], srstd[64];
  u16* wA0 = smem + 4608;
  u16* wA1 = wA0 + 8192;
  u16* wB0 = wA1 + 8192;
  u16* wB1 = wB0 + 8192;
  const int tid  = threadIdx.x;
  const int wave = tid >> 6, lane = tid & 63, quad = lane >> 4, l15 = lane & 15;
  const int m0 = wave * 16;
  u16* sYw = smem + wave*1152;
  const size_t rows0 = (size_t)blockIdx.x * 64;

  s8v aX[4];
  {
    const float* xr = xmid + (rows0 + m0 + l15)*(size_t)DM;
    #pragma unroll
    for (int ks = 0; ks < 4; ks++){
      #pragma unroll
      for (int j = 0; j < 8; j++){
        int c = ks*32 + quad*8 + j;
        float v = (c < DM) ? xr[c] : 0.f;
        aX[ks][j] = (short)f2bf(v);
      }
    }
  }
  stage_w1_256(w1t, 0, wA0, wave, lane);
  stage_w2_256(w2t, 0, wB0, wave, lane);
  __syncthreads();

  const float* b1l = b1 + (size_t)layer*DFF;
  const f4v z4 = {0.f, 0.f, 0.f, 0.f};
  f4v acc2[8];
  #pragma unroll
  for (int t = 0; t < 8; t++) acc2[t] = z4;

  for (int j = 0; j < 32; j++){
    u16* wAcur = (j & 1) ? wA1 : wA0;
    u16* wAnxt = (j & 1) ? wA0 : wA1;
    u16* wBcur = (j & 1) ? wB1 : wB0;
    u16* wBnxt = (j & 1) ? wB0 : wB1;
    if (j < 31){
      stage_w1_256(w1t, j+1, wAnxt, wave, lane);
      stage_w2_256(w2t, j+1, wBnxt, wave, lane);
    }
    f4v acc1[4];
    #pragma unroll
    for (int t = 0; t < 4; t++) acc1[t] = z4;
    #pragma unroll
    for (int ks = 0; ks < 4; ks++){
      #pragma unroll
      for (int t = 0; t < 4; t++){
        int nloc = t*16 + l15;
        int cg = (ks*4 + quad) ^ (nloc & 7);
        s8v b = *reinterpret_cast<const s8v*>(wAcur + nloc*128 + cg*8);
        acc1[t] = __builtin_amdgcn_mfma_f32_16x16x32_bf16(aX[ks], b, acc1[t], 0, 0, 0);
      }
    }
    #pragma unroll
    for (int t = 0; t < 4; t++){
      float bv = b1l[j*64 + t*16 + l15];
      #pragma unroll
      for (int r = 0; r < 4; r++){
        float v = gelu_fast(acc1[t][r] + bv);
        sYw[(quad*4 + r)*72 + t*16 + l15] = f2bf(v);
      }
    }
    #pragma unroll
    for (int ks = 0; ks < 2; ks++){
      s8v a2 = *reinterpret_cast<const s8v*>(sYw + l15*72 + ks*32 + quad*8);
      #pragma unroll
      for (int t = 0; t < 8; t++){
        int nloc = t*16 + l15;
        int cg = (ks*4 + quad) ^ (nloc & 7);
        s8v b = *reinterpret_cast<const s8v*>(wBcur + nloc*64 + cg*8);
        acc2[t] = __builtin_amdgcn_mfma_f32_16x16x32_bf16(a2, b, acc2[t], 0, 0, 0);
      }
    }
    __syncthreads();
  }

  float* sO = reinterpret_cast<float*>(smem);
  #pragma unroll
  for (int t = 0; t < 8; t++){
    int col = t*16 + l15;
    #pragma unroll
    for (int r = 0; r < 4; r++){
      sO[(m0 + quad*4 + r)*129 + col] = acc2[t][r];
    }
  }
  __syncthreads();
  const float* b2l = b2w + (size_t)layer*DM;
  for (int p = tid; p < 64*DM; p += 256){
    int r = p / DM, c = p - r*DM;
    sO[r*129 + c] += b2l[c] + xmid[(rows0 + r)*DM + c];
  }
  __syncthreads();
  if (tid < 128){
    int row = tid >> 1, half = tid & 1;
    float s = 0.f;
    for (int c = half*63; c < half*63 + 63; c++) s += sO[row*129 + c];
    prs[tid] = s;
  }
  __syncthreads();
  if (tid < 128 && (tid & 1) == 0) smean[tid>>1] = (prs[tid] + prs[tid+1]) / (float)DM;
  __syncthreads();
  if (tid < 128){
    int row = tid >> 1, half = tid & 1;
    float mn = smean[row];
    float s = 0.f;
    for (int c = half*63; c < half*63 + 63; c++){ float d = sO[row*129 + c] - mn; s += d*d; }
    prs[tid] = s;
  }
  __syncthreads();
  if (tid < 128 && (tid & 1) == 0) srstd[tid>>1] = rsqrtf((prs[tid] + prs[tid+1])/(float)DM + 1e-5f);
  __syncthreads();
  const float* gl = g  + (size_t)layer*DM;
  const float* bl = bb + (size_t)layer*DM;
  for (int p = tid; p < 64*DM; p += 256){
    int r = p / DM, c = p - r*DM;
    xout[(rows0 + r)*DM + c] = (sO[r*129 + c] - smean[r])*srstd[r]*gl[c] + bl[c];
  }
}

// ---------------- MFMA distil: conv(K=378) + BN + ELU + maxpool ----------------
__global__ __launch_bounds__(256) void k_distill_mfma(const float* xin, const u16* wdist,
                                                      fp clb, fp bng, fp bnb, float* xout){
  __shared__ __align__(16) u16 sA[128*392];
  const int tid = threadIdx.x;
  const int wave = tid >> 6, lane = tid & 63, quad = lane >> 4, l15 = lane & 15;
  const int b = blockIdx.x;
  for (int row = wave; row < 128; row += 4){
    #pragma unroll
    for (int e = 0; e < 6; e++){
      int kk = lane + e*64;
      float v = 0.f;
      if (kk < 378){
        int q = kk / 126, ci = kk - q*126;
        int sr = (row - 1 + q + 128) & 127;
        v = xin[((size_t)b*128 + sr)*DM + ci];
      }
      sA[row*392 + kk] = f2bf(v);
    }
  }
  __syncthreads();
  const f4v z4 = {0.f,0.f,0.f,0.f};
  f4v acc[2][8];
  #pragma unroll
  for (int m = 0; m < 2; m++)
    #pragma unroll
    for (int t = 0; t < 8; t++) acc[m][t] = z4;
  const int mBase = wave * 32;
  for (int ks = 0; ks < 12; ks++){
    s8v a0 = *reinterpret_cast<const s8v*>(sA + (mBase + l15)*392 + ks*32 + quad*8);
    s8v a1 = *reinterpret_cast<const s8v*>(sA + (mBase + 16 + l15)*392 + ks*32 + quad*8);
    const u16* wb = wdist + (size_t)l15*384 + ks*32 + quad*8;
    #pragma unroll
    for (int t = 0; t < 8; t++){
      s8v bfr = *reinterpret_cast<const s8v*>(wb + (size_t)t*16*384);
      acc[0][t] = __builtin_amdgcn_mfma_f32_16x16x32_bf16(a0, bfr, acc[0][t], 0, 0, 0);
      acc[1][t] = __builtin_amdgcn_mfma_f32_16x16x32_bf16(a1, bfr, acc[1][t], 0, 0, 0);
    }
  }
  __syncthreads();
  float* zsh = reinterpret_cast<float*>(sA);
  const float bnscale = 1.f / sqrtf(1.f + 1e-5f);
  #pragma unroll
  for (int t = 0; t < 8; t++){
    int co = t*16 + l15;
    if (co < DM){
      float cb = clb[co];
      float gg = bng[co] * bnscale, bv = bnb[co];
      #pragma unroll
      for (int m = 0; m < 2; m++){
        #pragma unroll
        for (int r = 0; r < 4; r++){
          int row = mBase + m*16 + quad*4 + r;
          float z = (acc[m][t][r] + cb)*gg + bv;
          z = (z > 0.f) ? z : expm1f(z);
          zsh[row*130 + co] = z;
        }
      }
    }
  }
  __syncthreads();
  for (int p = tid; p < 64*DM; p += 256){
    int j = p / DM, co = p - j*DM;
    float best = zsh[(2*j)*130 + co];
    if (j > 0) best = fmaxf(best, zsh[(2*j - 1)*130 + co]);
    best = fmaxf(best, zsh[(2*j + 1)*130 + co]);
    xout[((size_t)b*64 + j)*DM + co] = best;
  }
}

// ---------------- final LN + fc ----------------
__global__ __launch_bounds__(128) void k_final(const float* xin, fp g, fp bb,
                                               fp fcw, fp fcb, float* out){
  __shared__ float xs[64][DM];
  __shared__ float mean_s[64], rstd_s[64];
  int b = blockIdx.x, t = threadIdx.x;
  for (int p = t; p < 64*DM; p += 128){ xs[p/DM][p%DM] = xin[(size_t)b*64*DM + p]; }
  __syncthreads();
  if (t < 64){
    float s = 0.f;
    for (int m = 0; m < DM; m++) s += xs[t][m];
    float mn = s / (float)DM;
    float v = 0.f;
    for (int m = 0; m < DM; m++){ float d = xs[t][m] - mn; v += d*d; }
    mean_s[t] = mn; rstd_s[t] = rsqrtf(v / (float)DM + 1e-5f);
  }
  __syncthreads();
  if (t < DM){
    float gv = g[t], bv = bb[t];
    float acc = fcb[0];
    for (int l = 0; l < 64; l++){
      float xn = (xs[l][t] - mean_s[l])*rstd_s[l]*gv + bv;
      acc += xn * fcw[l];
    }
    out[b*DM + t] = acc;
  }
}

// ---------------- host launcher ----------------
extern "C" void kernel_launch(void* const* d_in, const int* in_sizes, int n_in,
                              void* d_out, int out_size, void* d_ws, size_t ws_size,
                              hipStream_t stream) {
  fp x_enc   = (fp)d_in[0];
  fp x_mark  = (fp)d_in[1];
  fp token_w = (fp)d_in[2];
  fp time_w  = (fp)d_in[3];
  fp time_b  = (fp)d_in[4];
  fp od_fc_w = (fp)d_in[5];
  fp od_bn_g = (fp)d_in[6];
  fp od_bn_b = (fp)d_in[7];
  fp od_ch_w = (fp)d_in[8];
  fp od_ch_b = (fp)d_in[9];
  fp od_fil_w= (fp)d_in[10];
  fp od_fil_b= (fp)d_in[11];
  fp od_sp_w = (fp)d_in[12];
  fp od_sp_b = (fp)d_in[13];
  fp od_ker_w= (fp)d_in[14];
  fp od_ker_b= (fp)d_in[15];
  fp od_wt   = (fp)d_in[16];
  fp q_w = (fp)d_in[17]; fp q_b = (fp)d_in[18];
  fp k_w = (fp)d_in[19]; fp k_b = (fp)d_in[20];
  fp v_w = (fp)d_in[21]; fp v_b = (fp)d_in[22];
  fp o_w = (fp)d_in[23]; fp o_b = (fp)d_in[24];
  fp f1w = (fp)d_in[25]; fp f1b = (fp)d_in[26];
  fp f2w = (fp)d_in[27]; fp f2b = (fp)d_in[28];
  fp ln1g= (fp)d_in[29]; fp ln1b= (fp)d_in[30];
  fp ln2g= (fp)d_in[31]; fp ln2b= (fp)d_in[32];
  fp cl_w= (fp)d_in[33]; fp cl_b= (fp)d_in[34];
  fp clbg= (fp)d_in[35]; fp clbb= (fp)d_in[36];
  fp elng= (fp)d_in[37]; fp elnb= (fp)d_in[38];
  fp fc_w= (fp)d_in[39]; fp fc_b= (fp)d_in[40];

  // ---- workspace layout (float units) ----
  const size_t OFF_IDX0 = 0;
  const size_t OFF_IDX1 = OFF_IDX0 + 3200;
  const size_t OFF_CH   = OFF_IDX1 + 1600;
  const size_t OFF_FIL  = OFF_CH  + (size_t)NB*DE;
  const size_t OFF_SP   = OFF_FIL + (size_t)NB*DE;
  const size_t OFF_KER  = OFF_SP  + (size_t)NB*4;
  const size_t OFF_VM   = OFF_KER + (size_t)NB*4;
  const size_t OFF_POS  = OFF_VM  + (size_t)NB*NH*DHd;
  const size_t OFF_UPD  = OFF_POS + (size_t)NB*NH*L0;
  const size_t OFF_STOP = OFF_UPD + (size_t)NB*NH*NTOP*DHd;
  const size_t OFF_WTS  = (OFF_STOP + (size_t)NB*NH*NTOP + 255) & ~(size_t)255;
  const size_t WTS_FLOATS = (2*262144 + 2*262144 + 2*49152 + 2*16384 + 49152 + 32768)/2 + 2*384;
  const size_t OFF_BIG  = (OFF_WTS + WTS_FLOATS + 255) & ~(size_t)255;
  const size_t SBUF     = (size_t)NB*DE*L0;
  const size_t TOTAL    = OFF_BIG + 4*SBUF;

  if (ws_size < TOTAL*sizeof(float)){
    hipLaunchKernelGGL(k_zero, dim3((out_size+255)/256), dim3(256), 0, stream,
                       (float*)d_out, out_size);
    return;
  }

  float* ws = (float*)d_ws;
  int* idx0 = (int*)(ws + OFF_IDX0);
  int* idx1 = (int*)(ws + OFF_IDX1);
  float* chv = ws + OFF_CH;
  float* filv= ws + OFF_FIL;
  float* spv = ws + OFF_SP;
  float* kerv= ws + OFF_KER;
  float* vme = ws + OFF_VM;
  int* posm  = (int*)(ws + OFF_POS);
  float* updb= ws + OFF_UPD;
  int* stopb = (int*)(ws + OFF_STOP);
  u16* w1tb  = (u16*)(ws + OFF_WTS);
  u16* w2tb  = w1tb + 2*262144;
  u16* wqkvb = w2tb + 2*262144;
  u16* wob   = wqkvb + 2*49152;
  u16* wdistb= wob + 2*16384;
  u16* wembb = wdistb + 49152;
  float* qkvbias = (float*)(wembb + 32768);

  float* X    = ws + OFF_BIG;
  float* QKV  = X + SBUF;
  float* emb  = QKV;
  float* xmid = QKV;
  float* ffno = QKV + SBUF;

  hipLaunchKernelGGL(k_idx, dim3(1), dim3(256), 0, stream, idx0, idx1);
  hipLaunchKernelGGL(k_wprep, dim3(4931), dim3(256), 0, stream,
                     token_w, cl_w, q_w, q_b, k_w, k_b, v_w, v_b, o_w, f1w, f2w,
                     wembb, wdistb, wqkvb, wob, w1tb, w2tb, qkvbias);
  hipLaunchKernelGGL(k_emb_mfma, dim3(NB), dim3(256), 0, stream,
                     x_enc, x_mark, wembb, time_w, time_b, emb);
  hipLaunchKernelGGL(k_scalars, dim3(NB), dim3(128), 0, stream,
                     emb, od_fc_w, od_bn_g, od_bn_b, od_ch_w, od_ch_b, od_fil_w, od_fil_b,
                     od_sp_w, od_sp_b, od_ker_w, od_ker_b, chv, filv, spv, kerv);
  hipLaunchKernelGGL(k_odconv_mfma, dim3(NB), dim3(256), 0, stream,
                     emb, od_wt, chv, filv, spv, kerv, X);

  // ----- layer 0 (L=128) -----
  hipLaunchKernelGGL(k_qkv_mfma, dim3(NB*L0/64), dim3(256), 0, stream,
                     X, wqkvb, qkvbias, QKV);
  hipLaunchKernelGGL(k_attn_sel, dim3(NB*NH/4), dim3(256), 0, stream,
                     QKV, idx0, L0, posm, stopb);
  hipLaunchKernelGGL(k_attn_pv, dim3(NB*NH/4), dim3(256), 0, stream,
                     QKV, stopb, L0, vme, updb);
  hipLaunchKernelGGL(k_oproj_mfma, dim3(NB*L0/64), dim3(256), 0, stream,
                     X, vme, posm, updb, wob, o_b, ln1g, ln1b, 0, 7, 127, xmid);
  hipLaunchKernelGGL(k_ffn_mfma, dim3(NB*L0/128), dim3(512), 0, stream,
                     xmid, w1tb, w2tb, f1b, f2b, ln2g, ln2b, 0, ffno);

  // ----- distil -----
  hipLaunchKernelGGL(k_distill_mfma, dim3(NB), dim3(256), 0, stream,
                     ffno, wdistb, cl_b, clbg, clbb, X);

  // ----- layer 1 (L=64) -----
  hipLaunchKernelGGL(k_qkv_mfma, dim3(NB*64/64), dim3(256), 0, stream,
                     X, wqkvb + 49152, qkvbias + 384, QKV);
  hipLaunchKernelGGL(k_attn_sel, dim3(NB*NH/4), dim3(256), 0, stream,
                     QKV, idx1, 64, posm, stopb);
  hipLaunchKernelGGL(k_attn_pv, dim3(NB*NH/4), dim3(256), 0, stream,
                     QKV, stopb, 64, vme, updb);
  hipLaunchKernelGGL(k_oproj_mfma, dim3(NB*64/64), dim3(256), 0, stream,
                     X, vme, posm, updb, wob + 16384, o_b, ln1g, ln1b, 1, 6, 63, xmid);
  hipLaunchKernelGGL(k_ffn_mfma256, dim3(NB*64/64), dim3(256), 0, stream,
                     xmid, w1tb + 262144, w2tb + 262144, f1b, f2b, ln2g, ln2b, 1, ffno);

  hipLaunchKernelGGL(k_final, dim3(NB), dim3(128), 0, stream,
                     ffno, elng, elnb, fc_w, fc_b, (float*)d_out);
  (void)in_sizes; (void)n_in; (void)out_size; (void)ws_size;
}